// Round 6
// baseline (96.895 us; speedup 1.0000x reference)
//
#include <hip/hip_runtime.h>
#include <hip/hip_bf16.h>

// Problem constants
#define B 4
#define N 2048
#define D 512
#define H 8
#define DH 64
#define ROWS (B * N)        // 8192
#define WIN 64              // r<=0.764 -> r^64 ~ 3e-8
#define QB 8                // query rows per wave in attn_sweep
#define NPAD (N + 2 * WIN)  // 2176 padded rows per batch in Vp

using bf16x8 = __attribute__((ext_vector_type(8))) short;
using f32x4  = __attribute__((ext_vector_type(4))) float;

static __device__ __forceinline__ unsigned short f2bf(float f) {
    unsigned u = __builtin_bit_cast(unsigned, f);
    u += 0x7fffu + ((u >> 16) & 1u);        // round-to-nearest-even
    return (unsigned short)(u >> 16);
}
static __device__ __forceinline__ unsigned pack2(float a, float b) {
    return (unsigned)f2bf(a) | ((unsigned)f2bf(b) << 16);
}
static __device__ __forceinline__ float bfhi(unsigned u) {   // high bf16 -> f32
    return __builtin_bit_cast(float, u & 0xffff0000u);
}
static __device__ __forceinline__ float bflo(unsigned u) {   // low bf16 -> f32
    return __builtin_bit_cast(float, u << 16);
}

// ------------- fused: x f32 -> bf16  AND  sigma -> l2r = log2(r) --------------
// one wave per row; lane covers 8 consecutive elements
__global__ __launch_bounds__(256) void prep_x(const float* __restrict__ x,
                                              const float* __restrict__ Ws,
                                              const float* __restrict__ bs,
                                              unsigned short* __restrict__ xbf,
                                              float* __restrict__ l2rbuf) {
    const int wid = threadIdx.x >> 6, lane = threadIdx.x & 63;
    const int row = blockIdx.x * 4 + wid;
    const float* xr = x + (size_t)row * D + lane * 8;
    const float4 a = *reinterpret_cast<const float4*>(xr);
    const float4 c = *reinterpret_cast<const float4*>(xr + 4);
    float v[8] = {a.x, a.y, a.z, a.w, c.x, c.y, c.z, c.w};

    // bf16 store
    uint4 o;
    o.x = pack2(v[0], v[1]); o.y = pack2(v[2], v[3]);
    o.z = pack2(v[4], v[5]); o.w = pack2(v[6], v[7]);
    *reinterpret_cast<uint4*>(xbf + (size_t)row * D + lane * 8) = o;

    // sigma partial dot: 8 heads via two float4 accumulators
    const float4* Ws4 = reinterpret_cast<const float4*>(Ws);   // (D, 8) -> 2 float4/row
    f32x4 alo = (f32x4)0.0f, ahi = (f32x4)0.0f;
#pragma unroll
    for (int j = 0; j < 8; j++) {
        const int e = lane * 8 + j;
        const float4 wl = Ws4[e * 2], wh = Ws4[e * 2 + 1];
        alo[0] += v[j] * wl.x; alo[1] += v[j] * wl.y; alo[2] += v[j] * wl.z; alo[3] += v[j] * wl.w;
        ahi[0] += v[j] * wh.x; ahi[1] += v[j] * wh.y; ahi[2] += v[j] * wh.z; ahi[3] += v[j] * wh.w;
    }
#pragma unroll
    for (int off = 1; off < 64; off <<= 1) {
#pragma unroll
        for (int c2 = 0; c2 < 4; c2++) {
            alo[c2] += __shfl_xor(alo[c2], off, 64);
            ahi[c2] += __shfl_xor(ahi[c2], off, 64);
        }
    }
    if (lane < 8) {
        const int h = lane;
        const float acc = (h < 4) ? alo[h] : ahi[h - 4];
        const float z = acc + bs[h];
        const float sig = 1.0f / (1.0f + expf(-z));
        const float s = expf(sig) + 1.0f;
        l2rbuf[(size_t)row * H + h] = -1.4426950408889634f / s;
    }
}

// ---------------- W (512x512 f32, KxN) -> W^T (NxK bf16) ----------------------
__global__ __launch_bounds__(256) void transpose_cvt(const float* __restrict__ Wv,
                                                     const float* __restrict__ Wo,
                                                     unsigned short* __restrict__ WvT,
                                                     unsigned short* __restrict__ WoT) {
    const float* src = blockIdx.z ? Wo : Wv;
    unsigned short* dst = blockIdx.z ? WoT : WvT;
    __shared__ float tile[64][65];
    const int n0 = blockIdx.x * 64, k0 = blockIdx.y * 64;
    const int tr = threadIdx.x >> 4, tc = threadIdx.x & 15;
#pragma unroll
    for (int it = 0; it < 4; it++) {
        const int r = it * 16 + tr;
        const float4 v = *reinterpret_cast<const float4*>(&src[(size_t)(k0 + r) * 512 + n0 + tc * 4]);
        tile[r][tc * 4 + 0] = v.x; tile[r][tc * 4 + 1] = v.y;
        tile[r][tc * 4 + 2] = v.z; tile[r][tc * 4 + 3] = v.w;
    }
    __syncthreads();
#pragma unroll
    for (int it = 0; it < 4; it++) {
        const int r = it * 16 + tr;
        ushort4 o;
        o.x = f2bf(tile[tc * 4 + 0][r]); o.y = f2bf(tile[tc * 4 + 1][r]);
        o.z = f2bf(tile[tc * 4 + 2][r]); o.w = f2bf(tile[tc * 4 + 3][r]);
        *reinterpret_cast<ushort4*>(&dst[(size_t)(n0 + r) * 512 + k0 + tc * 4]) = o;
    }
}

// ---------------- zero the pad rows of Vp -------------------------------------
// 512 pad rows (4 batches x 128) x 512 ushort; 16B per thread
__global__ __launch_bounds__(256) void zero_pads(unsigned short* __restrict__ Vp) {
    const int t = blockIdx.x * 256 + threadIdx.x;   // 0 .. 512*64-1
    const int rowid = t >> 6, c = t & 63;
    const int b = rowid >> 7, p = rowid & 127;
    const int prow = b * NPAD + (p < WIN ? p : p + N);
    *reinterpret_cast<uint4*>(Vp + (size_t)prow * D + c * 8) = uint4{0, 0, 0, 0};
}

// ---------------- bf16 MFMA GEMM, double-buffered LDS -------------------------
// C[M,Nn] = A[M,K] @ Bt[Nn,K]^T ; MODE 0: f32 out + bias; MODE 1: bf16 out, padded rows
#define GBM 128
#define GBN 64
#define GBK 64

template <int MODE>
__global__ __launch_bounds__(256) void gemm_bf16(const unsigned short* __restrict__ A,
                                                 const unsigned short* __restrict__ Bt,
                                                 const float* __restrict__ bias,
                                                 void* __restrict__ Cout,
                                                 int M, int Nn, int K) {
    __shared__ unsigned short As[2][GBM][GBK];   // 32 KB
    __shared__ unsigned short Bs[2][GBN][GBK];   // 16 KB
    const int tid = threadIdx.x;
    const int lane = tid & 63, wid = tid >> 6;
    const int wr = wid >> 1, wc = wid & 1;       // 2x2 waves: 64x32 each
    const int bm = blockIdx.y, bn = blockIdx.x;
    const int fr = lane & 15, kg = lane >> 4;

    f32x4 acc[4][2] = {};

    const unsigned short* Ab = A + (size_t)bm * GBM * K;
    const unsigned short* Bb = Bt + (size_t)bn * GBN * K;
    const int r8 = tid >> 3, c8 = (tid & 7) * 8;

    auto stage = [&](int buf, int k0) {
#pragma unroll
        for (int it = 0; it < 4; it++) {
            const unsigned short* g = Ab + (size_t)(it * 32 + r8) * K + k0 + c8;
            __builtin_amdgcn_global_load_lds(
                (const __attribute__((address_space(1))) void*)g,
                (__attribute__((address_space(3))) void*)&As[buf][it * 32 + r8][c8], 16, 0, 0);
        }
#pragma unroll
        for (int it = 0; it < 2; it++) {
            const unsigned short* g = Bb + (size_t)(it * 32 + r8) * K + k0 + c8;
            __builtin_amdgcn_global_load_lds(
                (const __attribute__((address_space(1))) void*)g,
                (__attribute__((address_space(3))) void*)&Bs[buf][it * 32 + r8][c8], 16, 0, 0);
        }
    };

    stage(0, 0);
    __syncthreads();
    int cur = 0;
    for (int k0 = 0; k0 < K; k0 += GBK) {
        if (k0 + GBK < K) stage(cur ^ 1, k0 + GBK);   // async loads overlap compute
#pragma unroll
        for (int ks = 0; ks < 2; ks++) {
            bf16x8 af[4], bfr[2];
#pragma unroll
            for (int m = 0; m < 4; m++)
                af[m] = *reinterpret_cast<const bf16x8*>(&As[cur][wr * 64 + m * 16 + fr][ks * 32 + kg * 8]);
#pragma unroll
            for (int n = 0; n < 2; n++)
                bfr[n] = *reinterpret_cast<const bf16x8*>(&Bs[cur][wc * 32 + n * 16 + fr][ks * 32 + kg * 8]);
#pragma unroll
            for (int m = 0; m < 4; m++)
#pragma unroll
                for (int n = 0; n < 2; n++)
                    acc[m][n] = __builtin_amdgcn_mfma_f32_16x16x32_bf16(af[m], bfr[n], acc[m][n], 0, 0, 0);
        }
        __syncthreads();   // drains next-tile loads (they had the compute phase to land)
        cur ^= 1;
    }

#pragma unroll
    for (int n = 0; n < 2; n++) {
        const int col = bn * GBN + wc * 32 + n * 16 + fr;
        const float bv = (MODE == 0 && bias) ? bias[col] : 0.0f;
#pragma unroll
        for (int m = 0; m < 4; m++) {
            const int row0 = bm * GBM + wr * 64 + m * 16 + kg * 4;
#pragma unroll
            for (int j = 0; j < 4; j++) {
                const int row = row0 + j;
                if (MODE == 0) {
                    ((float*)Cout)[(size_t)row * Nn + col] = acc[m][n][j] + bv;
                } else {
                    const int orow = row + ((row >> 11) << 7) + WIN;   // padded layout
                    ((unsigned short*)Cout)[(size_t)orow * Nn + col] = f2bf(acc[m][n][j]);
                }
            }
        }
    }
}

// ---------------- j-sweep attention: 8 j-rows per bf16x8 load-step ------------
// lane = g*8+q: g = j-row in 8-group, q = dh octet. All waves fully unrolled
// (V is zero-padded by WIN rows per batch; zero rows contribute nothing).
__global__ __launch_bounds__(256) void attn_sweep(const unsigned short* __restrict__ Vp,
                                                  const float* __restrict__ l2rbuf,
                                                  unsigned short* __restrict__ O) {
    const int wid = threadIdx.x >> 6;
    const int lane = threadIdx.x & 63;
    const int g = lane >> 3;            // j sub-offset 0..7
    const int q = lane & 7;             // dh octet 0..7
    const int gi = blockIdx.x * 4 + wid;       // over (b,h,iblk)
    const int iblk = gi & 255;          // N/QB = 256
    const int bh = gi >> 8;
    const int h = bh & 7;
    const int b = bh >> 3;
    const int i0 = iblk * QB;

    // first loaded row: j = i0 - 64 + g  ->  padded row b*NPAD + i0 + g
    const unsigned short* p = Vp + ((size_t)b * NPAD + i0 + g) * D + h * DH + q * 8;

    float l2r[QB];
#pragma unroll
    for (int k = 0; k < QB; k++)
        l2r[k] = l2rbuf[((size_t)(b * N + i0 + k)) * H + h];

    float acc[QB][8];
#pragma unroll
    for (int k = 0; k < QB; k++)
#pragma unroll
        for (int e = 0; e < 8; e++) acc[k][e] = 0.0f;

    float w[QB], wm[QB];

#define LOADV(OFFROWS)                                                          \
    const uint4 u = *reinterpret_cast<const uint4*>(p + (size_t)(OFFROWS) * D); \
    float v[8];                                                                 \
    v[0] = bflo(u.x); v[1] = bfhi(u.x); v[2] = bflo(u.y); v[3] = bfhi(u.y);     \
    v[4] = bflo(u.z); v[5] = bfhi(u.z); v[6] = bflo(u.w); v[7] = bfhi(u.w);

    // Phase A: 8 steps, j = i0-64+s*8+g, dist = 64 - 8s - g + k
#pragma unroll
    for (int k = 0; k < QB; k++) {
        w[k] = exp2f(l2r[k] * (float)(WIN - g + k));
        wm[k] = exp2f(-8.0f * l2r[k]);
    }
#pragma unroll
    for (int s = 0; s < 8; s++) {
        LOADV(s * 8)
#pragma unroll
        for (int k = 0; k < QB; k++) {
#pragma unroll
            for (int e = 0; e < 8; e++) acc[k][e] += w[k] * v[e];
            w[k] *= wm[k];
        }
    }

    // Phase B: 1 step, j = i0+g, d = |g-k| (exp2f(0)=1 exact at j==i)
    {
        LOADV(64)
#pragma unroll
        for (int k = 0; k < QB; k++) {
            const int d = (g > k) ? (g - k) : (k - g);
            const float wb = exp2f(l2r[k] * (float)d);
#pragma unroll
            for (int e = 0; e < 8; e++) acc[k][e] += wb * v[e];
        }
    }

    // Phase C: 8 steps, j = i0+8+s*8+g, dist = 8 + 8s + g - k
#pragma unroll
    for (int k = 0; k < QB; k++) {
        w[k] = exp2f(l2r[k] * (float)(QB + g - k));
        wm[k] = exp2f(8.0f * l2r[k]);
    }
#pragma unroll
    for (int s = 0; s < 8; s++) {
        LOADV(72 + s * 8)
#pragma unroll
        for (int k = 0; k < QB; k++) {
#pragma unroll
            for (int e = 0; e < 8; e++) acc[k][e] += w[k] * v[e];
            w[k] *= wm[k];
        }
    }
#undef LOADV

    // reduce across the 8 g-groups (butterfly over lane bits 3..5)
#pragma unroll
    for (int k = 0; k < QB; k++)
#pragma unroll
        for (int e = 0; e < 8; e++) {
            float t = acc[k][e];
            t += __shfl_xor(t, 8, 64);
            t += __shfl_xor(t, 16, 64);
            t += __shfl_xor(t, 32, 64);
            acc[k][e] = t;
        }

    // lane-group g stores row k == g; closed-form softmax denominator (exact)
#pragma unroll
    for (int k = 0; k < QB; k++) {
        if (k == g) {
            const int i = i0 + k;
            const float rr = exp2f(l2r[k]);
            const float inv1mr = 1.0f / (1.0f - rr);
            const float rl = exp2f(l2r[k] * (float)(i + 1));
            const float rg = exp2f(l2r[k] * (float)(N - i));
            const float z = 1.0f + (rr - rl) * inv1mr + (rr - rg) * inv1mr;
            const float invz = 1.0f / z;
            uint4 o;
            o.x = pack2(acc[k][0] * invz, acc[k][1] * invz);
            o.y = pack2(acc[k][2] * invz, acc[k][3] * invz);
            o.z = pack2(acc[k][4] * invz, acc[k][5] * invz);
            o.w = pack2(acc[k][6] * invz, acc[k][7] * invz);
            *reinterpret_cast<uint4*>(&O[((size_t)(b * N + i)) * D + h * DH + q * 8]) = o;
        }
    }
}

extern "C" void kernel_launch(void* const* d_in, const int* in_sizes, int n_in,
                              void* d_out, int out_size, void* d_ws, size_t ws_size,
                              hipStream_t stream) {
    const float* x      = (const float*)d_in[0];   // (B,N,D)
    const float* W_v    = (const float*)d_in[1];   // (D, 512)
    const float* W_sig  = (const float*)d_in[2];   // (D, H)
    const float* b_sig  = (const float*)d_in[3];   // (H,)
    const float* W_out  = (const float*)d_in[4];   // (512, D)
    const float* b_out  = (const float*)d_in[5];   // (D,)
    float* out = (float*)d_out;

    char* ws = (char*)d_ws;
    unsigned short* Vp   = (unsigned short*)ws;                                // 4*2176*512*2B = 8.5 MB
    unsigned short* xbf  = (unsigned short*)(ws + (size_t)9  * 1024 * 1024);   // 8 MB (reused as attnOut)
    unsigned short* WvT  = (unsigned short*)(ws + (size_t)17 * 1024 * 1024);   // 512 KB
    unsigned short* WoT  = (unsigned short*)(ws + (size_t)17 * 1024 * 1024 + 524288);
    float*          l2r  = (float*)(ws + (size_t)18 * 1024 * 1024);            // 256 KB
    unsigned short* attnOut = xbf;

    prep_x<<<ROWS / 4, 256, 0, stream>>>(x, W_sig, b_sig, xbf, l2r);
    {
        dim3 grid(8, 8, 2);
        transpose_cvt<<<grid, 256, 0, stream>>>(W_v, W_out, WvT, WoT);
    }
    zero_pads<<<128, 256, 0, stream>>>(Vp);

    // 1) Vp = x @ W_v  (bf16, padded rows)
    {
        dim3 grid(D / GBN, ROWS / GBM);
        gemm_bf16<1><<<grid, 256, 0, stream>>>(xbf, WvT, nullptr, Vp, ROWS, D, D);
    }
    // 2) windowed attention -> bf16
    attn_sweep<<<B * H * (N / QB) / 4, 256, 0, stream>>>(Vp, l2r, attnOut);
    // 3) out = attnOut @ W_out + b_out  (f32)
    {
        dim3 grid(D / GBN, ROWS / GBM);
        gemm_bf16<0><<<grid, 256, 0, stream>>>(attnOut, WoT, b_out, out, ROWS, D, D);
    }
}

// Round 7
// 69.430 us; speedup vs baseline: 1.3956x; 1.3956x over previous
//
#include <hip/hip_runtime.h>
#include <hip/hip_bf16.h>

// Problem constants
#define B 4
#define N 2048
#define D 512
#define H 8
#define DH 64
#define ROWS (B * N)        // 8192
#define WIN 64              // r<=0.764 -> r^64 ~ 3e-8
#define LPAD 64             // left col pad in Vt
#define RPAD 128            // right col pad in Vt (band reaches i0+95)
#define SEG (LPAD + N + RPAD)   // 2240 cols per batch in Vt
#define LDV (B * SEG)           // 8960 = Vt row length

using bf16x8 = __attribute__((ext_vector_type(8))) short;
using f32x4  = __attribute__((ext_vector_type(4))) float;

static __device__ __forceinline__ unsigned short f2bf(float f) {
    unsigned u = __builtin_bit_cast(unsigned, f);
    u += 0x7fffu + ((u >> 16) & 1u);        // round-to-nearest-even
    return (unsigned short)(u >> 16);
}
static __device__ __forceinline__ unsigned pack2(float a, float b) {
    return (unsigned)f2bf(a) | ((unsigned)f2bf(b) << 16);
}

// ------------- fused: x f32 -> bf16  AND  sigma -> l2r = log2(r) --------------
__global__ __launch_bounds__(256) void prep_x(const float* __restrict__ x,
                                              const float* __restrict__ Ws,
                                              const float* __restrict__ bs,
                                              unsigned short* __restrict__ xbf,
                                              float* __restrict__ l2rbuf) {
    const int wid = threadIdx.x >> 6, lane = threadIdx.x & 63;
    const int row = blockIdx.x * 4 + wid;
    const float* xr = x + (size_t)row * D + lane * 8;
    const float4 a = *reinterpret_cast<const float4*>(xr);
    const float4 c = *reinterpret_cast<const float4*>(xr + 4);
    float v[8] = {a.x, a.y, a.z, a.w, c.x, c.y, c.z, c.w};

    uint4 o;
    o.x = pack2(v[0], v[1]); o.y = pack2(v[2], v[3]);
    o.z = pack2(v[4], v[5]); o.w = pack2(v[6], v[7]);
    *reinterpret_cast<uint4*>(xbf + (size_t)row * D + lane * 8) = o;

    const float4* Ws4 = reinterpret_cast<const float4*>(Ws);   // (D, 8)
    f32x4 alo = (f32x4)0.0f, ahi = (f32x4)0.0f;
#pragma unroll
    for (int j = 0; j < 8; j++) {
        const int e = lane * 8 + j;
        const float4 wl = Ws4[e * 2], wh = Ws4[e * 2 + 1];
        alo[0] += v[j] * wl.x; alo[1] += v[j] * wl.y; alo[2] += v[j] * wl.z; alo[3] += v[j] * wl.w;
        ahi[0] += v[j] * wh.x; ahi[1] += v[j] * wh.y; ahi[2] += v[j] * wh.z; ahi[3] += v[j] * wh.w;
    }
#pragma unroll
    for (int off = 1; off < 64; off <<= 1) {
#pragma unroll
        for (int c2 = 0; c2 < 4; c2++) {
            alo[c2] += __shfl_xor(alo[c2], off, 64);
            ahi[c2] += __shfl_xor(ahi[c2], off, 64);
        }
    }
    if (lane < 8) {
        const int h = lane;
        const float acc = (h < 4) ? alo[h] : ahi[h - 4];
        const float z = acc + bs[h];
        const float sig = 1.0f / (1.0f + expf(-z));
        const float s = expf(sig) + 1.0f;
        l2rbuf[(size_t)row * H + h] = -1.4426950408889634f / s;
    }
}

// -------- W transposes (z=0,1)  +  Vt pad-column zeroing (z=2) ----------------
__global__ __launch_bounds__(256) void transpose_cvt(const float* __restrict__ Wv,
                                                     const float* __restrict__ Wo,
                                                     unsigned short* __restrict__ WvT,
                                                     unsigned short* __restrict__ WoT,
                                                     unsigned short* __restrict__ Vt) {
    if (blockIdx.z == 2) {
        // zero pad cols of Vt: per row per batch, 24 chunks of 16B (8 left, 16 right)
        const int blk = blockIdx.x + 8 * blockIdx.y;   // 0..63
        for (int t = blk * 256 + threadIdx.x; t < 512 * 4 * 24; t += 64 * 256) {
            const int c = t % 24;
            const int bb = (t / 24) & 3;
            const int row = t / 96;
            const int col = (c < 8) ? bb * SEG + c * 8 : bb * SEG + LPAD + N + (c - 8) * 8;
            *reinterpret_cast<uint4*>(Vt + (size_t)row * LDV + col) = uint4{0, 0, 0, 0};
        }
        return;
    }
    const float* src = blockIdx.z ? Wo : Wv;
    unsigned short* dst = blockIdx.z ? WoT : WvT;
    __shared__ float tile[64][65];
    const int n0 = blockIdx.x * 64, k0 = blockIdx.y * 64;
    const int tr = threadIdx.x >> 4, tc = threadIdx.x & 15;
#pragma unroll
    for (int it = 0; it < 4; it++) {
        const int r = it * 16 + tr;
        const float4 v = *reinterpret_cast<const float4*>(&src[(size_t)(k0 + r) * 512 + n0 + tc * 4]);
        tile[r][tc * 4 + 0] = v.x; tile[r][tc * 4 + 1] = v.y;
        tile[r][tc * 4 + 2] = v.z; tile[r][tc * 4 + 3] = v.w;
    }
    __syncthreads();
#pragma unroll
    for (int it = 0; it < 4; it++) {
        const int r = it * 16 + tr;
        ushort4 o;
        o.x = f2bf(tile[tc * 4 + 0][r]); o.y = f2bf(tile[tc * 4 + 1][r]);
        o.z = f2bf(tile[tc * 4 + 2][r]); o.w = f2bf(tile[tc * 4 + 3][r]);
        *reinterpret_cast<ushort4*>(&dst[(size_t)(n0 + r) * 512 + k0 + tc * 4]) = o;
    }
}

// ---------------- bf16 MFMA GEMM, double-buffered LDS -------------------------
// C[M,Nn] = A[M,K] @ Bt[Nn,K]^T
// MODE 0: f32 out + bias, ldc = Nn.  MODE 2: bf16 out into Vt with col remap.
#define GBM 128
#define GBN 64
#define GBK 64

template <int MODE>
__global__ __launch_bounds__(256) void gemm_bf16(const unsigned short* __restrict__ A,
                                                 const unsigned short* __restrict__ Bt,
                                                 const float* __restrict__ bias,
                                                 void* __restrict__ Cout,
                                                 int M, int Nn, int K, int ldc) {
    __shared__ unsigned short As[2][GBM][GBK];   // 32 KB
    __shared__ unsigned short Bs[2][GBN][GBK];   // 16 KB
    const int tid = threadIdx.x;
    const int lane = tid & 63, wid = tid >> 6;
    const int wr = wid >> 1, wc = wid & 1;       // 2x2 waves: 64x32 each
    const int bm = blockIdx.y, bn = blockIdx.x;
    const int fr = lane & 15, kg = lane >> 4;

    f32x4 acc[4][2] = {};

    const unsigned short* Ab = A + (size_t)bm * GBM * K;
    const unsigned short* Bb = Bt + (size_t)bn * GBN * K;
    const int r8 = tid >> 3, c8 = (tid & 7) * 8;

    auto stage = [&](int buf, int k0) {
#pragma unroll
        for (int it = 0; it < 4; it++) {
            const unsigned short* g = Ab + (size_t)(it * 32 + r8) * K + k0 + c8;
            __builtin_amdgcn_global_load_lds(
                (const __attribute__((address_space(1))) void*)g,
                (__attribute__((address_space(3))) void*)&As[buf][it * 32 + r8][c8], 16, 0, 0);
        }
#pragma unroll
        for (int it = 0; it < 2; it++) {
            const unsigned short* g = Bb + (size_t)(it * 32 + r8) * K + k0 + c8;
            __builtin_amdgcn_global_load_lds(
                (const __attribute__((address_space(1))) void*)g,
                (__attribute__((address_space(3))) void*)&Bs[buf][it * 32 + r8][c8], 16, 0, 0);
        }
    };

    stage(0, 0);
    __syncthreads();
    int cur = 0;
    for (int k0 = 0; k0 < K; k0 += GBK) {
        if (k0 + GBK < K) stage(cur ^ 1, k0 + GBK);
#pragma unroll
        for (int ks = 0; ks < 2; ks++) {
            bf16x8 af[4], bfr[2];
#pragma unroll
            for (int m = 0; m < 4; m++)
                af[m] = *reinterpret_cast<const bf16x8*>(&As[cur][wr * 64 + m * 16 + fr][ks * 32 + kg * 8]);
#pragma unroll
            for (int n = 0; n < 2; n++)
                bfr[n] = *reinterpret_cast<const bf16x8*>(&Bs[cur][wc * 32 + n * 16 + fr][ks * 32 + kg * 8]);
#pragma unroll
            for (int m = 0; m < 4; m++)
#pragma unroll
                for (int n = 0; n < 2; n++)
                    acc[m][n] = __builtin_amdgcn_mfma_f32_16x16x32_bf16(af[m], bfr[n], acc[m][n], 0, 0, 0);
        }
        __syncthreads();
        cur ^= 1;
    }

#pragma unroll
    for (int n = 0; n < 2; n++) {
        const int col = bn * GBN + wc * 32 + n * 16 + fr;
        const float bv = (MODE == 0 && bias) ? bias[col] : 0.0f;
        const int cp = (MODE == 2) ? ((col >> 11) * SEG + LPAD + (col & 2047)) : col;
#pragma unroll
        for (int m = 0; m < 4; m++) {
            const int row0 = bm * GBM + wr * 64 + m * 16 + kg * 4;
#pragma unroll
            for (int j = 0; j < 4; j++) {
                const int row = row0 + j;
                if (MODE == 0)
                    ((float*)Cout)[(size_t)row * ldc + col] = acc[m][n][j] + bv;
                else
                    ((unsigned short*)Cout)[(size_t)row * ldc + cp] = f2bf(acc[m][n][j]);
            }
        }
    }
}

// ---------------- MFMA banded attention ---------------------------------------
// wave -> (b, h, 16-row i-tile). O^T(64d x 16i) = Vt(64d x 160j) * P^T(160j x 16i)
// P^T built in-register: w = exp2(l2r_i * |i-j|); Z closed-form exact.
__global__ __launch_bounds__(256) void attn_mfma(const unsigned short* __restrict__ Vt,
                                                 const float* __restrict__ l2rbuf,
                                                 unsigned short* __restrict__ O) {
    const int wid = threadIdx.x >> 6;
    const int lane = threadIdx.x & 63;
    const int fr = lane & 15, kg = lane >> 4;
    const int gi = blockIdx.x * 4 + wid;       // over (b,h,iblk)
    const int iblk = gi & 127;                 // N/16 = 128
    const int bh = gi >> 7;
    const int h = bh & 7;
    const int b = bh >> 3;
    const int i0 = iblk * 16;

    const int i = i0 + fr;                              // this lane's query row
    const float l2rf = l2rbuf[((size_t)(b * N + i)) * H + h];

    // Vt base for this wave's A-fragments: row h*64 + fr, padded col b*SEG + i0 + kg*8
    const unsigned short* Vrow = Vt + (size_t)(h * DH + fr) * LDV + (size_t)b * SEG + i0 + kg * 8;

    f32x4 acc[4] = {};

#pragma unroll
    for (int s = 0; s < 5; s++) {
        // B-frag: 8 weights for j = i0 - 64 + s*32 + kg*8 + j2, query row i
        const float basef = (float)(s * 32 + kg * 8 - WIN - fr);
        float wv[8];
#pragma unroll
        for (int j2 = 0; j2 < 8; j2++)
            wv[j2] = __builtin_amdgcn_exp2f(l2rf * __builtin_fabsf(basef + (float)j2));
        uint4 uw;
        uw.x = pack2(wv[0], wv[1]); uw.y = pack2(wv[2], wv[3]);
        uw.z = pack2(wv[4], wv[5]); uw.w = pack2(wv[6], wv[7]);
        const bf16x8 pB = __builtin_bit_cast(bf16x8, uw);
#pragma unroll
        for (int sub = 0; sub < 4; sub++) {
            const bf16x8 aF = *reinterpret_cast<const bf16x8*>(Vrow + (size_t)(sub * 16) * LDV + s * 32);
            acc[sub] = __builtin_amdgcn_mfma_f32_16x16x32_bf16(aF, pB, acc[sub], 0, 0, 0);
        }
    }

    // closed-form softmax denominator (exact, full-N sum)
    const float rr = __builtin_amdgcn_exp2f(l2rf);
    const float inv1mr = 1.0f / (1.0f - rr);
    const float rl = __builtin_amdgcn_exp2f(l2rf * (float)(i + 1));
    const float rg = __builtin_amdgcn_exp2f(l2rf * (float)(N - i));
    const float invz = 1.0f / (1.0f + (2.0f * rr - rl - rg) * inv1mr);

    unsigned short* orow = O + ((size_t)(b * N + i)) * D + h * DH + kg * 4;
#pragma unroll
    for (int sub = 0; sub < 4; sub++) {
        uint2 o;
        o.x = pack2(acc[sub][0] * invz, acc[sub][1] * invz);
        o.y = pack2(acc[sub][2] * invz, acc[sub][3] * invz);
        *reinterpret_cast<uint2*>(orow + sub * 16) = o;
    }
}

extern "C" void kernel_launch(void* const* d_in, const int* in_sizes, int n_in,
                              void* d_out, int out_size, void* d_ws, size_t ws_size,
                              hipStream_t stream) {
    const float* x      = (const float*)d_in[0];   // (B,N,D)
    const float* W_v    = (const float*)d_in[1];   // (D, 512)
    const float* W_sig  = (const float*)d_in[2];   // (D, H)
    const float* b_sig  = (const float*)d_in[3];   // (H,)
    const float* W_out  = (const float*)d_in[4];   // (512, D)
    const float* b_out  = (const float*)d_in[5];   // (D,)
    float* out = (float*)d_out;

    char* ws = (char*)d_ws;
    unsigned short* Vt   = (unsigned short*)ws;                                // 512*8960*2B = 8.75 MB
    unsigned short* xbf  = (unsigned short*)(ws + (size_t)9  * 1024 * 1024);   // 8 MB (reused as attnOut)
    unsigned short* WvT  = (unsigned short*)(ws + (size_t)17 * 1024 * 1024);   // 512 KB
    unsigned short* WoT  = (unsigned short*)(ws + (size_t)17 * 1024 * 1024 + 524288);
    float*          l2r  = (float*)(ws + (size_t)18 * 1024 * 1024);            // 256 KB
    unsigned short* attnOut = xbf;   // xbf dead after GEMM1

    prep_x<<<ROWS / 4, 256, 0, stream>>>(x, W_sig, b_sig, xbf, l2r);
    {
        dim3 grid(8, 8, 3);   // z=0: WvT, z=1: WoT, z=2: zero Vt pads
        transpose_cvt<<<grid, 256, 0, stream>>>(W_v, W_out, WvT, WoT, Vt);
    }

    // 1) Vt = (x @ W_v)^T, bf16, column-padded per batch
    {
        dim3 grid(ROWS / GBN, 512 / GBM);
        gemm_bf16<2><<<grid, 256, 0, stream>>>(WvT, xbf, nullptr, Vt, 512, ROWS, D, LDV);
    }
    // 2) banded MFMA attention -> bf16 row-major O
    attn_mfma<<<B * H * (N / 16) / 4, 256, 0, stream>>>(Vt, l2r, attnOut);
    // 3) out = attnOut @ W_out + b_out  (f32)
    {
        dim3 grid(D / GBN, ROWS / GBM);
        gemm_bf16<0><<<grid, 256, 0, stream>>>(attnOut, WoT, b_out, out, ROWS, D, D, D);
    }
}

// Round 8
// 68.133 us; speedup vs baseline: 1.4221x; 1.0190x over previous
//
#include <hip/hip_runtime.h>
#include <hip/hip_bf16.h>

// Problem constants
#define B 4
#define N 2048
#define D 512
#define H 8
#define DH 64
#define ROWS (B * N)        // 8192
#define WIN 64              // r<=0.764 -> r^64 ~ 3e-8
#define LPAD 64             // left col pad in Vt
#define RPAD 128            // right col pad in Vt (band reaches i0+95)
#define SEG (LPAD + N + RPAD)   // 2240 cols per batch in Vt
#define LDV (B * SEG)           // 8960 = Vt row length

using bf16x8 = __attribute__((ext_vector_type(8))) short;
using f32x4  = __attribute__((ext_vector_type(4))) float;

static __device__ __forceinline__ unsigned short f2bf(float f) {
    unsigned u = __builtin_bit_cast(unsigned, f);
    u += 0x7fffu + ((u >> 16) & 1u);        // round-to-nearest-even
    return (unsigned short)(u >> 16);
}
static __device__ __forceinline__ unsigned pack2(float a, float b) {
    return (unsigned)f2bf(a) | ((unsigned)f2bf(b) << 16);
}

// ------------- fused prep: x->bf16 + sigma (blocks 0..2047),
//               WvT (2048..2111), WoT (2112..2175), Vt pad zero (2176..2239) ---
__global__ __launch_bounds__(256) void prep_fused(const float* __restrict__ x,
                                                  const float* __restrict__ Ws,
                                                  const float* __restrict__ bs,
                                                  const float* __restrict__ Wv,
                                                  const float* __restrict__ Wo,
                                                  unsigned short* __restrict__ xbf,
                                                  float* __restrict__ l2rbuf,
                                                  unsigned short* __restrict__ WvT,
                                                  unsigned short* __restrict__ WoT,
                                                  unsigned short* __restrict__ Vt) {
    __shared__ float tile[64][65];
    const int bx = blockIdx.x;

    if (bx < 2048) {
        // ---- x convert + sigma ----
        const int wid = threadIdx.x >> 6, lane = threadIdx.x & 63;
        const int row = bx * 4 + wid;
        const float* xr = x + (size_t)row * D + lane * 8;
        const float4 a = *reinterpret_cast<const float4*>(xr);
        const float4 c = *reinterpret_cast<const float4*>(xr + 4);
        float v[8] = {a.x, a.y, a.z, a.w, c.x, c.y, c.z, c.w};

        uint4 o;
        o.x = pack2(v[0], v[1]); o.y = pack2(v[2], v[3]);
        o.z = pack2(v[4], v[5]); o.w = pack2(v[6], v[7]);
        *reinterpret_cast<uint4*>(xbf + (size_t)row * D + lane * 8) = o;

        const float4* Ws4 = reinterpret_cast<const float4*>(Ws);   // (D, 8)
        f32x4 alo = (f32x4)0.0f, ahi = (f32x4)0.0f;
#pragma unroll
        for (int j = 0; j < 8; j++) {
            const int e = lane * 8 + j;
            const float4 wl = Ws4[e * 2], wh = Ws4[e * 2 + 1];
            alo[0] += v[j] * wl.x; alo[1] += v[j] * wl.y; alo[2] += v[j] * wl.z; alo[3] += v[j] * wl.w;
            ahi[0] += v[j] * wh.x; ahi[1] += v[j] * wh.y; ahi[2] += v[j] * wh.z; ahi[3] += v[j] * wh.w;
        }
#pragma unroll
        for (int off = 1; off < 64; off <<= 1) {
#pragma unroll
            for (int c2 = 0; c2 < 4; c2++) {
                alo[c2] += __shfl_xor(alo[c2], off, 64);
                ahi[c2] += __shfl_xor(ahi[c2], off, 64);
            }
        }
        if (lane < 8) {
            const int h = lane;
            const float acc = (h < 4) ? alo[h] : ahi[h - 4];
            const float z = acc + bs[h];
            const float sig = 1.0f / (1.0f + expf(-z));
            const float s = expf(sig) + 1.0f;
            l2rbuf[(size_t)row * H + h] = -1.4426950408889634f / s;
        }
        return;
    }

    if (bx < 2176) {
        // ---- W transpose+convert ----
        const int idx = bx - 2048;
        const bool second = idx >= 64;
        const int id2 = idx & 63;
        const float* src = second ? Wo : Wv;
        unsigned short* dst = second ? WoT : WvT;
        const int n0 = (id2 & 7) * 64, k0 = (id2 >> 3) * 64;
        const int tr = threadIdx.x >> 4, tc = threadIdx.x & 15;
#pragma unroll
        for (int it = 0; it < 4; it++) {
            const int r = it * 16 + tr;
            const float4 v = *reinterpret_cast<const float4*>(&src[(size_t)(k0 + r) * 512 + n0 + tc * 4]);
            tile[r][tc * 4 + 0] = v.x; tile[r][tc * 4 + 1] = v.y;
            tile[r][tc * 4 + 2] = v.z; tile[r][tc * 4 + 3] = v.w;
        }
        __syncthreads();
#pragma unroll
        for (int it = 0; it < 4; it++) {
            const int r = it * 16 + tr;
            ushort4 o;
            o.x = f2bf(tile[tc * 4 + 0][r]); o.y = f2bf(tile[tc * 4 + 1][r]);
            o.z = f2bf(tile[tc * 4 + 2][r]); o.w = f2bf(tile[tc * 4 + 3][r]);
            *reinterpret_cast<ushort4*>(&dst[(size_t)(n0 + r) * 512 + k0 + tc * 4]) = o;
        }
        return;
    }

    // ---- zero pad cols of Vt ----
    {
        const int idx = bx - 2176;   // 0..63
        for (int t = idx * 256 + threadIdx.x; t < 512 * 4 * 24; t += 64 * 256) {
            const int c = t % 24;
            const int bb = (t / 24) & 3;
            const int row = t / 96;
            const int col = (c < 8) ? bb * SEG + c * 8 : bb * SEG + LPAD + N + (c - 8) * 8;
            *reinterpret_cast<uint4*>(Vt + (size_t)row * LDV + col) = uint4{0, 0, 0, 0};
        }
    }
}

// ---------------- bf16 MFMA GEMM, 128x128 tile, double-buffered LDS -----------
// C[M,Nn] = A[M,K] @ Bt[Nn,K]^T
// MODE 0: f32 out + bias, ldc = Nn.  MODE 2: bf16 out into Vt with col remap.
#define GBM 128
#define GBN 128
#define GBK 64

template <int MODE>
__global__ __launch_bounds__(256) void gemm_bf16(const unsigned short* __restrict__ A,
                                                 const unsigned short* __restrict__ Bt,
                                                 const float* __restrict__ bias,
                                                 void* __restrict__ Cout,
                                                 int M, int Nn, int K, int ldc) {
    __shared__ unsigned short As[2][GBM][GBK];   // 32 KB
    __shared__ unsigned short Bs[2][GBN][GBK];   // 32 KB
    const int tid = threadIdx.x;
    const int lane = tid & 63, wid = tid >> 6;
    const int wr = wid >> 1, wc = wid & 1;       // 2x2 waves: 64x64 each
    const int bm = blockIdx.y, bn = blockIdx.x;
    const int fr = lane & 15, kg = lane >> 4;

    f32x4 acc[4][4] = {};

    const unsigned short* Ab = A + (size_t)bm * GBM * K;
    const unsigned short* Bb = Bt + (size_t)bn * GBN * K;
    const int r8 = tid >> 3, c8 = (tid & 7) * 8;

    auto stage = [&](int buf, int k0) {
#pragma unroll
        for (int it = 0; it < 4; it++) {
            const unsigned short* g = Ab + (size_t)(it * 32 + r8) * K + k0 + c8;
            __builtin_amdgcn_global_load_lds(
                (const __attribute__((address_space(1))) void*)g,
                (__attribute__((address_space(3))) void*)&As[buf][it * 32 + r8][c8], 16, 0, 0);
        }
#pragma unroll
        for (int it = 0; it < 4; it++) {
            const unsigned short* g = Bb + (size_t)(it * 32 + r8) * K + k0 + c8;
            __builtin_amdgcn_global_load_lds(
                (const __attribute__((address_space(1))) void*)g,
                (__attribute__((address_space(3))) void*)&Bs[buf][it * 32 + r8][c8], 16, 0, 0);
        }
    };

    stage(0, 0);
    __syncthreads();
    int cur = 0;
    for (int k0 = 0; k0 < K; k0 += GBK) {
        if (k0 + GBK < K) stage(cur ^ 1, k0 + GBK);
#pragma unroll
        for (int ks = 0; ks < 2; ks++) {
            bf16x8 af[4], bfr[4];
#pragma unroll
            for (int m = 0; m < 4; m++)
                af[m] = *reinterpret_cast<const bf16x8*>(&As[cur][wr * 64 + m * 16 + fr][ks * 32 + kg * 8]);
#pragma unroll
            for (int n = 0; n < 4; n++)
                bfr[n] = *reinterpret_cast<const bf16x8*>(&Bs[cur][wc * 64 + n * 16 + fr][ks * 32 + kg * 8]);
#pragma unroll
            for (int m = 0; m < 4; m++)
#pragma unroll
                for (int n = 0; n < 4; n++)
                    acc[m][n] = __builtin_amdgcn_mfma_f32_16x16x32_bf16(af[m], bfr[n], acc[m][n], 0, 0, 0);
        }
        __syncthreads();
        cur ^= 1;
    }

#pragma unroll
    for (int n = 0; n < 4; n++) {
        const int col = bn * GBN + wc * 64 + n * 16 + fr;
        const float bv = (MODE == 0 && bias) ? bias[col] : 0.0f;
        const int cp = (MODE == 2) ? ((col >> 11) * SEG + LPAD + (col & 2047)) : col;
#pragma unroll
        for (int m = 0; m < 4; m++) {
            const int row0 = bm * GBM + wr * 64 + m * 16 + kg * 4;
#pragma unroll
            for (int j = 0; j < 4; j++) {
                const int row = row0 + j;
                if (MODE == 0)
                    ((float*)Cout)[(size_t)row * ldc + col] = acc[m][n][j] + bv;
                else
                    ((unsigned short*)Cout)[(size_t)row * ldc + cp] = f2bf(acc[m][n][j]);
            }
        }
    }
}

// ---------------- MFMA banded attention ---------------------------------------
// wave -> (b, h, 16-row i-tile). O^T(64d x 16i) = Vt(64d x 160j) * P^T(160j x 16i)
__global__ __launch_bounds__(256) void attn_mfma(const unsigned short* __restrict__ Vt,
                                                 const float* __restrict__ l2rbuf,
                                                 unsigned short* __restrict__ O) {
    const int wid = threadIdx.x >> 6;
    const int lane = threadIdx.x & 63;
    const int fr = lane & 15, kg = lane >> 4;
    const int gi = blockIdx.x * 4 + wid;       // over (b,h,iblk)
    const int iblk = gi & 127;                 // N/16 = 128
    const int bh = gi >> 7;
    const int h = bh & 7;
    const int b = bh >> 3;
    const int i0 = iblk * 16;

    const int i = i0 + fr;                              // this lane's query row
    const float l2rf = l2rbuf[((size_t)(b * N + i)) * H + h];

    const unsigned short* Vrow = Vt + (size_t)(h * DH + fr) * LDV + (size_t)b * SEG + i0 + kg * 8;

    f32x4 acc[4] = {};

#pragma unroll
    for (int s = 0; s < 5; s++) {
        const float basef = (float)(s * 32 + kg * 8 - WIN - fr);
        float wv[8];
#pragma unroll
        for (int j2 = 0; j2 < 8; j2++)
            wv[j2] = __builtin_amdgcn_exp2f(l2rf * __builtin_fabsf(basef + (float)j2));
        uint4 uw;
        uw.x = pack2(wv[0], wv[1]); uw.y = pack2(wv[2], wv[3]);
        uw.z = pack2(wv[4], wv[5]); uw.w = pack2(wv[6], wv[7]);
        const bf16x8 pB = __builtin_bit_cast(bf16x8, uw);
#pragma unroll
        for (int sub = 0; sub < 4; sub++) {
            const bf16x8 aF = *reinterpret_cast<const bf16x8*>(Vrow + (size_t)(sub * 16) * LDV + s * 32);
            acc[sub] = __builtin_amdgcn_mfma_f32_16x16x32_bf16(aF, pB, acc[sub], 0, 0, 0);
        }
    }

    const float rr = __builtin_amdgcn_exp2f(l2rf);
    const float inv1mr = 1.0f / (1.0f - rr);
    const float rl = __builtin_amdgcn_exp2f(l2rf * (float)(i + 1));
    const float rg = __builtin_amdgcn_exp2f(l2rf * (float)(N - i));
    const float invz = 1.0f / (1.0f + (2.0f * rr - rl - rg) * inv1mr);

    unsigned short* orow = O + ((size_t)(b * N + i)) * D + h * DH + kg * 4;
#pragma unroll
    for (int sub = 0; sub < 4; sub++) {
        uint2 o;
        o.x = pack2(acc[sub][0] * invz, acc[sub][1] * invz);
        o.y = pack2(acc[sub][2] * invz, acc[sub][3] * invz);
        *reinterpret_cast<uint2*>(orow + sub * 16) = o;
    }
}

extern "C" void kernel_launch(void* const* d_in, const int* in_sizes, int n_in,
                              void* d_out, int out_size, void* d_ws, size_t ws_size,
                              hipStream_t stream) {
    const float* x      = (const float*)d_in[0];   // (B,N,D)
    const float* W_v    = (const float*)d_in[1];   // (D, 512)
    const float* W_sig  = (const float*)d_in[2];   // (D, H)
    const float* b_sig  = (const float*)d_in[3];   // (H,)
    const float* W_out  = (const float*)d_in[4];   // (512, D)
    const float* b_out  = (const float*)d_in[5];   // (D,)
    float* out = (float*)d_out;

    char* ws = (char*)d_ws;
    unsigned short* Vt   = (unsigned short*)ws;                                // 512*8960*2B = 8.75 MB
    unsigned short* xbf  = (unsigned short*)(ws + (size_t)9  * 1024 * 1024);   // 8 MB (reused as attnOut)
    unsigned short* WvT  = (unsigned short*)(ws + (size_t)17 * 1024 * 1024);   // 512 KB
    unsigned short* WoT  = (unsigned short*)(ws + (size_t)17 * 1024 * 1024 + 524288);
    float*          l2r  = (float*)(ws + (size_t)18 * 1024 * 1024);            // 256 KB
    unsigned short* attnOut = xbf;   // xbf dead after GEMM1

    prep_fused<<<2240, 256, 0, stream>>>(x, W_sig, b_sig, W_v, W_out,
                                         xbf, l2r, WvT, WoT, Vt);

    // 1) Vt = (x @ W_v)^T, bf16, column-padded per batch
    {
        dim3 grid(ROWS / GBN, 512 / GBM);
        gemm_bf16<2><<<grid, 256, 0, stream>>>(WvT, xbf, nullptr, Vt, 512, ROWS, D, LDV);
    }
    // 2) banded MFMA attention -> bf16 row-major O
    attn_mfma<<<B * H * (N / 16) / 4, 256, 0, stream>>>(Vt, l2r, attnOut);
    // 3) out = attnOut @ W_out + b_out  (f32)
    {
        dim3 grid(D / GBN, ROWS / GBM);
        gemm_bf16<0><<<grid, 256, 0, stream>>>(attnOut, WoT, b_out, out, ROWS, D, D, D);
    }
}

// Round 9
// 66.779 us; speedup vs baseline: 1.4510x; 1.0203x over previous
//
#include <hip/hip_runtime.h>
#include <hip/hip_bf16.h>

// Problem constants
#define B 4
#define N 2048
#define D 512
#define H 8
#define DH 64
#define ROWS (B * N)        // 8192
#define WIN 64              // r<=0.764 -> r^64 ~ 3e-8
#define LPAD 64             // left col pad in Vt
#define RPAD 128            // right col pad in Vt
#define SEG (LPAD + N + RPAD)   // 2240 cols per batch in Vt
#define LDV (B * SEG)           // 8960 = Vt row length

using bf16x8 = __attribute__((ext_vector_type(8))) short;
using f32x4  = __attribute__((ext_vector_type(4))) float;
using f32x16 = __attribute__((ext_vector_type(16))) float;

static __device__ __forceinline__ unsigned short f2bf(float f) {
    unsigned u = __builtin_bit_cast(unsigned, f);
    u += 0x7fffu + ((u >> 16) & 1u);        // round-to-nearest-even
    return (unsigned short)(u >> 16);
}
static __device__ __forceinline__ unsigned pack2(float a, float b) {
    return (unsigned)f2bf(a) | ((unsigned)f2bf(b) << 16);
}

// ------------- fused prep: x->bf16 + sigma (blocks 0..2047),
//               WvT (2048..2111), WoT (2112..2175), Vt pad zero (2176..2239) ---
__global__ __launch_bounds__(256) void prep_fused(const float* __restrict__ x,
                                                  const float* __restrict__ Ws,
                                                  const float* __restrict__ bs,
                                                  const float* __restrict__ Wv,
                                                  const float* __restrict__ Wo,
                                                  unsigned short* __restrict__ xbf,
                                                  float* __restrict__ l2rbuf,
                                                  unsigned short* __restrict__ WvT,
                                                  unsigned short* __restrict__ WoT,
                                                  unsigned short* __restrict__ Vt) {
    __shared__ float tile[64][65];
    const int bx = blockIdx.x;

    if (bx < 2048) {
        // ---- x convert + sigma ----
        const int wid = threadIdx.x >> 6, lane = threadIdx.x & 63;
        const int row = bx * 4 + wid;
        const float* xr = x + (size_t)row * D + lane * 8;
        const float4 a = *reinterpret_cast<const float4*>(xr);
        const float4 c = *reinterpret_cast<const float4*>(xr + 4);
        float v[8] = {a.x, a.y, a.z, a.w, c.x, c.y, c.z, c.w};

        uint4 o;
        o.x = pack2(v[0], v[1]); o.y = pack2(v[2], v[3]);
        o.z = pack2(v[4], v[5]); o.w = pack2(v[6], v[7]);
        *reinterpret_cast<uint4*>(xbf + (size_t)row * D + lane * 8) = o;

        const float4* Ws4 = reinterpret_cast<const float4*>(Ws);   // (D, 8)
        f32x4 alo = (f32x4)0.0f, ahi = (f32x4)0.0f;
#pragma unroll
        for (int j = 0; j < 8; j++) {
            const int e = lane * 8 + j;
            const float4 wl = Ws4[e * 2], wh = Ws4[e * 2 + 1];
            alo[0] += v[j] * wl.x; alo[1] += v[j] * wl.y; alo[2] += v[j] * wl.z; alo[3] += v[j] * wl.w;
            ahi[0] += v[j] * wh.x; ahi[1] += v[j] * wh.y; ahi[2] += v[j] * wh.z; ahi[3] += v[j] * wh.w;
        }
#pragma unroll
        for (int off = 1; off < 64; off <<= 1) {
#pragma unroll
            for (int c2 = 0; c2 < 4; c2++) {
                alo[c2] += __shfl_xor(alo[c2], off, 64);
                ahi[c2] += __shfl_xor(ahi[c2], off, 64);
            }
        }
        if (lane < 8) {
            const int h = lane;
            const float acc = (h < 4) ? alo[h] : ahi[h - 4];
            const float z = acc + bs[h];
            const float sig = 1.0f / (1.0f + expf(-z));
            const float s = expf(sig) + 1.0f;
            l2rbuf[(size_t)row * H + h] = -1.4426950408889634f / s;
        }
        return;
    }

    if (bx < 2176) {
        // ---- W transpose+convert ----
        const int idx = bx - 2048;
        const bool second = idx >= 64;
        const int id2 = idx & 63;
        const float* src = second ? Wo : Wv;
        unsigned short* dst = second ? WoT : WvT;
        const int n0 = (id2 & 7) * 64, k0 = (id2 >> 3) * 64;
        const int tr = threadIdx.x >> 4, tc = threadIdx.x & 15;
#pragma unroll
        for (int it = 0; it < 4; it++) {
            const int r = it * 16 + tr;
            const float4 v = *reinterpret_cast<const float4*>(&src[(size_t)(k0 + r) * 512 + n0 + tc * 4]);
            tile[r][tc * 4 + 0] = v.x; tile[r][tc * 4 + 1] = v.y;
            tile[r][tc * 4 + 2] = v.z; tile[r][tc * 4 + 3] = v.w;
        }
        __syncthreads();
#pragma unroll
        for (int it = 0; it < 4; it++) {
            const int r = it * 16 + tr;
            ushort4 o;
            o.x = f2bf(tile[tc * 4 + 0][r]); o.y = f2bf(tile[tc * 4 + 1][r]);
            o.z = f2bf(tile[tc * 4 + 2][r]); o.w = f2bf(tile[tc * 4 + 3][r]);
            *reinterpret_cast<ushort4*>(&dst[(size_t)(n0 + r) * 512 + k0 + tc * 4]) = o;
        }
        return;
    }

    // ---- zero pad cols of Vt ----
    {
        const int idx = bx - 2176;   // 0..63
        for (int t = idx * 256 + threadIdx.x; t < 512 * 4 * 24; t += 64 * 256) {
            const int c = t % 24;
            const int bb = (t / 24) & 3;
            const int row = t / 96;
            const int col = (c < 8) ? bb * SEG + c * 8 : bb * SEG + LPAD + N + (c - 8) * 8;
            *reinterpret_cast<uint4*>(Vt + (size_t)row * LDV + col) = uint4{0, 0, 0, 0};
        }
    }
}

// ---------------- bf16 MFMA GEMM, 128x128 tile, double-buffered LDS -----------
// C[M,Nn] = A[M,K] @ Bt[Nn,K]^T
// MODE 0: f32 out + bias, 1D grid with XCD swizzle (grid must be 256 = 4bn x 64bm).
// MODE 2: bf16 out into Vt with col remap, 2D grid.
#define GBM 128
#define GBN 128
#define GBK 64

template <int MODE>
__global__ __launch_bounds__(256) void gemm_bf16(const unsigned short* __restrict__ A,
                                                 const unsigned short* __restrict__ Bt,
                                                 const float* __restrict__ bias,
                                                 void* __restrict__ Cout,
                                                 int M, int Nn, int K, int ldc) {
    __shared__ unsigned short As[2][GBM][GBK];   // 32 KB
    __shared__ unsigned short Bs[2][GBN][GBK];   // 32 KB
    const int tid = threadIdx.x;
    const int lane = tid & 63, wid = tid >> 6;
    const int wr = wid >> 1, wc = wid & 1;       // 2x2 waves: 64x64 each
    int bm, bn;
    if (MODE == 0) {
        // XCD-grouping swizzle: colocate the 4 bn-blocks sharing an A-panel
        // (and 8 consecutive bm-panels) on one XCD. grid = 256, xcd = bid%8.
        const int swz = (blockIdx.x & 7) * 32 + (blockIdx.x >> 3);
        bm = swz >> 2; bn = swz & 3;
    } else {
        bm = blockIdx.y; bn = blockIdx.x;
    }
    const int fr = lane & 15, kg = lane >> 4;

    f32x4 acc[4][4] = {};

    const unsigned short* Ab = A + (size_t)bm * GBM * K;
    const unsigned short* Bb = Bt + (size_t)bn * GBN * K;
    const int r8 = tid >> 3, c8 = (tid & 7) * 8;

    auto stage = [&](int buf, int k0) {
#pragma unroll
        for (int it = 0; it < 4; it++) {
            const unsigned short* g = Ab + (size_t)(it * 32 + r8) * K + k0 + c8;
            __builtin_amdgcn_global_load_lds(
                (const __attribute__((address_space(1))) void*)g,
                (__attribute__((address_space(3))) void*)&As[buf][it * 32 + r8][c8], 16, 0, 0);
        }
#pragma unroll
        for (int it = 0; it < 4; it++) {
            const unsigned short* g = Bb + (size_t)(it * 32 + r8) * K + k0 + c8;
            __builtin_amdgcn_global_load_lds(
                (const __attribute__((address_space(1))) void*)g,
                (__attribute__((address_space(3))) void*)&Bs[buf][it * 32 + r8][c8], 16, 0, 0);
        }
    };

    stage(0, 0);
    __syncthreads();
    int cur = 0;
    for (int k0 = 0; k0 < K; k0 += GBK) {
        if (k0 + GBK < K) stage(cur ^ 1, k0 + GBK);
#pragma unroll
        for (int ks = 0; ks < 2; ks++) {
            bf16x8 af[4], bfr[4];
#pragma unroll
            for (int m = 0; m < 4; m++)
                af[m] = *reinterpret_cast<const bf16x8*>(&As[cur][wr * 64 + m * 16 + fr][ks * 32 + kg * 8]);
#pragma unroll
            for (int n = 0; n < 4; n++)
                bfr[n] = *reinterpret_cast<const bf16x8*>(&Bs[cur][wc * 64 + n * 16 + fr][ks * 32 + kg * 8]);
#pragma unroll
            for (int m = 0; m < 4; m++)
#pragma unroll
                for (int n = 0; n < 4; n++)
                    acc[m][n] = __builtin_amdgcn_mfma_f32_16x16x32_bf16(af[m], bfr[n], acc[m][n], 0, 0, 0);
        }
        __syncthreads();
        cur ^= 1;
    }

#pragma unroll
    for (int n = 0; n < 4; n++) {
        const int col = bn * GBN + wc * 64 + n * 16 + fr;
        const float bv = (MODE == 0 && bias) ? bias[col] : 0.0f;
        const int cp = (MODE == 2) ? ((col >> 11) * SEG + LPAD + (col & 2047)) : col;
#pragma unroll
        for (int m = 0; m < 4; m++) {
            const int row0 = bm * GBM + wr * 64 + m * 16 + kg * 4;
#pragma unroll
            for (int j = 0; j < 4; j++) {
                const int row = row0 + j;
                if (MODE == 0)
                    ((float*)Cout)[(size_t)row * ldc + col] = acc[m][n][j] + bv;
                else
                    ((unsigned short*)Cout)[(size_t)row * ldc + cp] = f2bf(acc[m][n][j]);
            }
        }
    }
}

// ---------------- MFMA banded attention, 32x32x16 -----------------------------
// wave -> (b, h, 32-row i-tile). O^T(64d x 32i) = Vt(64d x 160j) * P^T(160j x 32i)
// A/B frag: m(n)=lane&31, k=(lane>>5)*8+e. C/D: col=lane&31,
// row=(reg&3)+8*(reg>>2)+4*(lane>>5)  [m74/m101 verified].
__global__ __launch_bounds__(256) void attn_mfma(const unsigned short* __restrict__ Vt,
                                                 const float* __restrict__ l2rbuf,
                                                 unsigned short* __restrict__ O) {
    const int wid = threadIdx.x >> 6;
    const int lane = threadIdx.x & 63;
    const int il = lane & 31, hi = lane >> 5;
    const int gi = blockIdx.x * 4 + wid;       // over (b,h,iblk)
    const int iblk = gi & 63;                  // N/32 = 64
    const int bh = gi >> 6;
    const int h = bh & 7;
    const int b = bh >> 3;
    const int i0 = iblk * 32;

    const int i = i0 + il;                     // this lane's query row (C col)
    const float l2rf = l2rbuf[((size_t)(b * N + i)) * H + h];

    // A-frag base: Vt row (h*64 + il), padded col i0 + hi*8 (+ks*16)
    const unsigned short* Va = Vt + (size_t)(h * DH + il) * LDV + (size_t)b * SEG + i0 + hi * 8;

    f32x16 acc0 = (f32x16)0.0f, acc1 = (f32x16)0.0f;
    __builtin_amdgcn_s_setprio(1);
#pragma unroll
    for (int ks = 0; ks < 10; ks++) {
        // B-frag: 8 weights, j - i = ks*16 + hi*8 + e - WIN - il
        const float jb = (float)(ks * 16 + hi * 8 - WIN - il);
        float wv[8];
#pragma unroll
        for (int e = 0; e < 8; e++)
            wv[e] = __builtin_amdgcn_exp2f(l2rf * __builtin_fabsf(jb + (float)e));
        uint4 uw;
        uw.x = pack2(wv[0], wv[1]); uw.y = pack2(wv[2], wv[3]);
        uw.z = pack2(wv[4], wv[5]); uw.w = pack2(wv[6], wv[7]);
        const bf16x8 pB = __builtin_bit_cast(bf16x8, uw);
        const bf16x8 a0 = *reinterpret_cast<const bf16x8*>(Va + (size_t)ks * 16);
        const bf16x8 a1 = *reinterpret_cast<const bf16x8*>(Va + (size_t)32 * LDV + (size_t)ks * 16);
        acc0 = __builtin_amdgcn_mfma_f32_32x32x16_bf16(a0, pB, acc0, 0, 0, 0);
        acc1 = __builtin_amdgcn_mfma_f32_32x32x16_bf16(a1, pB, acc1, 0, 0, 0);
    }
    __builtin_amdgcn_s_setprio(0);

    // closed-form softmax denominator (exact, full-N sum); i fixed per lane
    const float rr = __builtin_amdgcn_exp2f(l2rf);
    const float inv1mr = 1.0f / (1.0f - rr);
    const float rl = __builtin_amdgcn_exp2f(l2rf * (float)(i + 1));
    const float rg = __builtin_amdgcn_exp2f(l2rf * (float)(N - i));
    const float invz = 1.0f / (1.0f + (2.0f * rr - rl - rg) * inv1mr);

    // store: d = dsub*32 + 4*hi + 8*q + (reg&3)
    unsigned short* orow = O + ((size_t)(b * N + i)) * D + h * DH + 4 * hi;
#pragma unroll
    for (int q = 0; q < 4; q++) {
        uint2 o0, o1;
        o0.x = pack2(acc0[4 * q + 0] * invz, acc0[4 * q + 1] * invz);
        o0.y = pack2(acc0[4 * q + 2] * invz, acc0[4 * q + 3] * invz);
        *reinterpret_cast<uint2*>(orow + 8 * q) = o0;
        o1.x = pack2(acc1[4 * q + 0] * invz, acc1[4 * q + 1] * invz);
        o1.y = pack2(acc1[4 * q + 2] * invz, acc1[4 * q + 3] * invz);
        *reinterpret_cast<uint2*>(orow + 32 + 8 * q) = o1;
    }
}

extern "C" void kernel_launch(void* const* d_in, const int* in_sizes, int n_in,
                              void* d_out, int out_size, void* d_ws, size_t ws_size,
                              hipStream_t stream) {
    const float* x      = (const float*)d_in[0];   // (B,N,D)
    const float* W_v    = (const float*)d_in[1];   // (D, 512)
    const float* W_sig  = (const float*)d_in[2];   // (D, H)
    const float* b_sig  = (const float*)d_in[3];   // (H,)
    const float* W_out  = (const float*)d_in[4];   // (512, D)
    const float* b_out  = (const float*)d_in[5];   // (D,)
    float* out = (float*)d_out;

    char* ws = (char*)d_ws;
    unsigned short* Vt   = (unsigned short*)ws;                                // 512*8960*2B = 8.75 MB
    unsigned short* xbf  = (unsigned short*)(ws + (size_t)9  * 1024 * 1024);   // 8 MB (reused as attnOut)
    unsigned short* WvT  = (unsigned short*)(ws + (size_t)17 * 1024 * 1024);   // 512 KB
    unsigned short* WoT  = (unsigned short*)(ws + (size_t)17 * 1024 * 1024 + 524288);
    float*          l2r  = (float*)(ws + (size_t)18 * 1024 * 1024);            // 256 KB
    unsigned short* attnOut = xbf;   // xbf dead after GEMM1

    prep_fused<<<2240, 256, 0, stream>>>(x, W_sig, b_sig, W_v, W_out,
                                         xbf, l2r, WvT, WoT, Vt);

    // 1) Vt = (x @ W_v)^T, bf16, column-padded per batch
    {
        dim3 grid(ROWS / GBN, 512 / GBM);
        gemm_bf16<2><<<grid, 256, 0, stream>>>(WvT, xbf, nullptr, Vt, 512, ROWS, D, LDV);
    }
    // 2) banded MFMA attention (32x32) -> bf16 row-major O
    attn_mfma<<<B * H * (N / 32) / 4, 256, 0, stream>>>(Vt, l2r, attnOut);
    // 3) out = attnOut @ W_out + b_out  (f32), XCD-swizzled 1D grid
    gemm_bf16<0><<<256, 256, 0, stream>>>(attnOut, WoT, b_out, out, ROWS, D, D, D);
}

// Round 10
// 66.520 us; speedup vs baseline: 1.4566x; 1.0039x over previous
//
#include <hip/hip_runtime.h>
#include <hip/hip_bf16.h>

// Problem constants
#define B 4
#define N 2048
#define D 512
#define H 8
#define DH 64
#define ROWS (B * N)        // 8192
#define WIN 64              // r<=0.764 -> r^64 ~ 3e-8
#define LPAD 64             // left col pad in Vt
#define RPAD 128            // right col pad in Vt
#define SEG (LPAD + N + RPAD)   // 2240 cols per batch in Vt
#define LDV (B * SEG)           // 8960 = Vt row length

using bf16x8 = __attribute__((ext_vector_type(8))) short;
using f32x4  = __attribute__((ext_vector_type(4))) float;
using f32x16 = __attribute__((ext_vector_type(16))) float;

static __device__ __forceinline__ unsigned short f2bf(float f) {
    unsigned u = __builtin_bit_cast(unsigned, f);
    u += 0x7fffu + ((u >> 16) & 1u);        // round-to-nearest-even
    return (unsigned short)(u >> 16);
}
static __device__ __forceinline__ unsigned pack2(float a, float b) {
    return (unsigned)f2bf(a) | ((unsigned)f2bf(b) << 16);
}

// ------------- fused prep: x->bf16 + sigma (blocks 0..2047),
//               WvT (2048..2111), WoT (2112..2175), Vt pad zero (2176..2239) ---
__global__ __launch_bounds__(256) void prep_fused(const float* __restrict__ x,
                                                  const float* __restrict__ Ws,
                                                  const float* __restrict__ bs,
                                                  const float* __restrict__ Wv,
                                                  const float* __restrict__ Wo,
                                                  unsigned short* __restrict__ xbf,
                                                  float* __restrict__ l2rbuf,
                                                  unsigned short* __restrict__ WvT,
                                                  unsigned short* __restrict__ WoT,
                                                  unsigned short* __restrict__ Vt) {
    __shared__ float tile[64][65];
    const int bx = blockIdx.x;

    if (bx < 2048) {
        // ---- x convert + sigma ----
        const int wid = threadIdx.x >> 6, lane = threadIdx.x & 63;
        const int row = bx * 4 + wid;
        const float* xr = x + (size_t)row * D + lane * 8;
        const float4 a = *reinterpret_cast<const float4*>(xr);
        const float4 c = *reinterpret_cast<const float4*>(xr + 4);
        float v[8] = {a.x, a.y, a.z, a.w, c.x, c.y, c.z, c.w};

        uint4 o;
        o.x = pack2(v[0], v[1]); o.y = pack2(v[2], v[3]);
        o.z = pack2(v[4], v[5]); o.w = pack2(v[6], v[7]);
        *reinterpret_cast<uint4*>(xbf + (size_t)row * D + lane * 8) = o;

        const float4* Ws4 = reinterpret_cast<const float4*>(Ws);   // (D, 8)
        f32x4 alo = (f32x4)0.0f, ahi = (f32x4)0.0f;
#pragma unroll
        for (int j = 0; j < 8; j++) {
            const int e = lane * 8 + j;
            const float4 wl = Ws4[e * 2], wh = Ws4[e * 2 + 1];
            alo[0] += v[j] * wl.x; alo[1] += v[j] * wl.y; alo[2] += v[j] * wl.z; alo[3] += v[j] * wl.w;
            ahi[0] += v[j] * wh.x; ahi[1] += v[j] * wh.y; ahi[2] += v[j] * wh.z; ahi[3] += v[j] * wh.w;
        }
#pragma unroll
        for (int off = 1; off < 64; off <<= 1) {
#pragma unroll
            for (int c2 = 0; c2 < 4; c2++) {
                alo[c2] += __shfl_xor(alo[c2], off, 64);
                ahi[c2] += __shfl_xor(ahi[c2], off, 64);
            }
        }
        if (lane < 8) {
            const int h = lane;
            const float acc = (h < 4) ? alo[h] : ahi[h - 4];
            const float z = acc + bs[h];
            const float sig = 1.0f / (1.0f + expf(-z));
            const float s = expf(sig) + 1.0f;
            l2rbuf[(size_t)row * H + h] = -1.4426950408889634f / s;
        }
        return;
    }

    if (bx < 2176) {
        // ---- W transpose+convert ----
        const int idx = bx - 2048;
        const bool second = idx >= 64;
        const int id2 = idx & 63;
        const float* src = second ? Wo : Wv;
        unsigned short* dst = second ? WoT : WvT;
        const int n0 = (id2 & 7) * 64, k0 = (id2 >> 3) * 64;
        const int tr = threadIdx.x >> 4, tc = threadIdx.x & 15;
#pragma unroll
        for (int it = 0; it < 4; it++) {
            const int r = it * 16 + tr;
            const float4 v = *reinterpret_cast<const float4*>(&src[(size_t)(k0 + r) * 512 + n0 + tc * 4]);
            tile[r][tc * 4 + 0] = v.x; tile[r][tc * 4 + 1] = v.y;
            tile[r][tc * 4 + 2] = v.z; tile[r][tc * 4 + 3] = v.w;
        }
        __syncthreads();
#pragma unroll
        for (int it = 0; it < 4; it++) {
            const int r = it * 16 + tr;
            ushort4 o;
            o.x = f2bf(tile[tc * 4 + 0][r]); o.y = f2bf(tile[tc * 4 + 1][r]);
            o.z = f2bf(tile[tc * 4 + 2][r]); o.w = f2bf(tile[tc * 4 + 3][r]);
            *reinterpret_cast<ushort4*>(&dst[(size_t)(n0 + r) * 512 + k0 + tc * 4]) = o;
        }
        return;
    }

    // ---- zero pad cols of Vt ----
    {
        const int idx = bx - 2176;   // 0..63
        for (int t = idx * 256 + threadIdx.x; t < 512 * 4 * 24; t += 64 * 256) {
            const int c = t % 24;
            const int bb = (t / 24) & 3;
            const int row = t / 96;
            const int col = (c < 8) ? bb * SEG + c * 8 : bb * SEG + LPAD + N + (c - 8) * 8;
            *reinterpret_cast<uint4*>(Vt + (size_t)row * LDV + col) = uint4{0, 0, 0, 0};
        }
    }
}

// ---------------- bf16 MFMA GEMM, 128x128 tile, GBK=128, double-buffered ------
// C[M,Nn] = A[M,K=512] @ Bt[Nn,K=512]^T ; 4 K-steps, 64 MFMA/wave/step.
// MODE 0: f32 out + bias, 1D grid with XCD swizzle (grid must be 256 = 4bn x 64bm).
// MODE 2: bf16 out into Vt with col remap, 2D grid.
#define GBM 128
#define GBN 128
#define GBK 128
#define GK  512

template <int MODE>
__global__ __launch_bounds__(256) void gemm_bf16(const unsigned short* __restrict__ A,
                                                 const unsigned short* __restrict__ Bt,
                                                 const float* __restrict__ bias,
                                                 void* __restrict__ Cout,
                                                 int Nn, int ldc) {
    __shared__ unsigned short As[2][GBM][GBK];   // 64 KB
    __shared__ unsigned short Bs[2][GBN][GBK];   // 64 KB  (128 KB total, 1 block/CU)
    const int tid = threadIdx.x;
    const int lane = tid & 63, wid = tid >> 6;
    const int wr = wid >> 1, wc = wid & 1;       // 2x2 waves: 64x64 each
    int bm, bn;
    if (MODE == 0) {
        // XCD-grouping swizzle: colocate the 4 bn-blocks sharing an A-panel.
        const int swz = (blockIdx.x & 7) * 32 + (blockIdx.x >> 3);
        bm = swz >> 2; bn = swz & 3;
    } else {
        bm = blockIdx.y; bn = blockIdx.x;
    }
    const int fr = lane & 15, kg = lane >> 4;

    f32x4 acc[4][4] = {};

    const unsigned short* Ab = A + (size_t)bm * GBM * GK;
    const unsigned short* Bb = Bt + (size_t)bn * GBN * GK;
    const int r16 = tid >> 4, c16 = (tid & 15) * 8;   // 16 rows/pass, 16B chunks

    auto stage = [&](int buf, int k0) {
#pragma unroll
        for (int it = 0; it < 8; it++) {
            const unsigned short* g = Ab + (size_t)(it * 16 + r16) * GK + k0 + c16;
            __builtin_amdgcn_global_load_lds(
                (const __attribute__((address_space(1))) void*)g,
                (__attribute__((address_space(3))) void*)&As[buf][it * 16 + r16][c16], 16, 0, 0);
        }
#pragma unroll
        for (int it = 0; it < 8; it++) {
            const unsigned short* g = Bb + (size_t)(it * 16 + r16) * GK + k0 + c16;
            __builtin_amdgcn_global_load_lds(
                (const __attribute__((address_space(1))) void*)g,
                (__attribute__((address_space(3))) void*)&Bs[buf][it * 16 + r16][c16], 16, 0, 0);
        }
    };

    stage(0, 0);
    __syncthreads();
    int cur = 0;
#pragma unroll
    for (int kt = 0; kt < GK / GBK; kt++) {
        if (kt + 1 < GK / GBK) stage(cur ^ 1, (kt + 1) * GBK);   // overlap with compute
#pragma unroll
        for (int ks = 0; ks < 4; ks++) {
            bf16x8 af[4], bfr[4];
#pragma unroll
            for (int m = 0; m < 4; m++)
                af[m] = *reinterpret_cast<const bf16x8*>(&As[cur][wr * 64 + m * 16 + fr][ks * 32 + kg * 8]);
#pragma unroll
            for (int n = 0; n < 4; n++)
                bfr[n] = *reinterpret_cast<const bf16x8*>(&Bs[cur][wc * 64 + n * 16 + fr][ks * 32 + kg * 8]);
#pragma unroll
            for (int m = 0; m < 4; m++)
#pragma unroll
                for (int n = 0; n < 4; n++)
                    acc[m][n] = __builtin_amdgcn_mfma_f32_16x16x32_bf16(af[m], bfr[n], acc[m][n], 0, 0, 0);
        }
        __syncthreads();
        cur ^= 1;
    }

#pragma unroll
    for (int n = 0; n < 4; n++) {
        const int col = bn * GBN + wc * 64 + n * 16 + fr;
        const float bv = (MODE == 0 && bias) ? bias[col] : 0.0f;
        const int cp = (MODE == 2) ? ((col >> 11) * SEG + LPAD + (col & 2047)) : col;
#pragma unroll
        for (int m = 0; m < 4; m++) {
            const int row0 = bm * GBM + wr * 64 + m * 16 + kg * 4;
#pragma unroll
            for (int j = 0; j < 4; j++) {
                const int row = row0 + j;
                if (MODE == 0)
                    ((float*)Cout)[(size_t)row * ldc + col] = acc[m][n][j] + bv;
                else
                    ((unsigned short*)Cout)[(size_t)row * ldc + cp] = f2bf(acc[m][n][j]);
            }
        }
    }
}

// ---------------- MFMA banded attention, 32x32x16 -----------------------------
// wave -> (b, h, 32-row i-tile). O^T(64d x 32i) = Vt(64d x 160j) * P^T(160j x 32i)
__global__ __launch_bounds__(256) void attn_mfma(const unsigned short* __restrict__ Vt,
                                                 const float* __restrict__ l2rbuf,
                                                 unsigned short* __restrict__ O) {
    const int wid = threadIdx.x >> 6;
    const int lane = threadIdx.x & 63;
    const int il = lane & 31, hi = lane >> 5;
    const int gi = blockIdx.x * 4 + wid;       // over (b,h,iblk)
    const int iblk = gi & 63;                  // N/32 = 64
    const int bh = gi >> 6;
    const int h = bh & 7;
    const int b = bh >> 3;
    const int i0 = iblk * 32;

    const int i = i0 + il;                     // this lane's query row (C col)
    const float l2rf = l2rbuf[((size_t)(b * N + i)) * H + h];

    const unsigned short* Va = Vt + (size_t)(h * DH + il) * LDV + (size_t)b * SEG + i0 + hi * 8;

    f32x16 acc0 = (f32x16)0.0f, acc1 = (f32x16)0.0f;
    __builtin_amdgcn_s_setprio(1);
#pragma unroll
    for (int ks = 0; ks < 10; ks++) {
        const float jb = (float)(ks * 16 + hi * 8 - WIN - il);
        float wv[8];
#pragma unroll
        for (int e = 0; e < 8; e++)
            wv[e] = __builtin_amdgcn_exp2f(l2rf * __builtin_fabsf(jb + (float)e));
        uint4 uw;
        uw.x = pack2(wv[0], wv[1]); uw.y = pack2(wv[2], wv[3]);
        uw.z = pack2(wv[4], wv[5]); uw.w = pack2(wv[6], wv[7]);
        const bf16x8 pB = __builtin_bit_cast(bf16x8, uw);
        const bf16x8 a0 = *reinterpret_cast<const bf16x8*>(Va + (size_t)ks * 16);
        const bf16x8 a1 = *reinterpret_cast<const bf16x8*>(Va + (size_t)32 * LDV + (size_t)ks * 16);
        acc0 = __builtin_amdgcn_mfma_f32_32x32x16_bf16(a0, pB, acc0, 0, 0, 0);
        acc1 = __builtin_amdgcn_mfma_f32_32x32x16_bf16(a1, pB, acc1, 0, 0, 0);
    }
    __builtin_amdgcn_s_setprio(0);

    const float rr = __builtin_amdgcn_exp2f(l2rf);
    const float inv1mr = 1.0f / (1.0f - rr);
    const float rl = __builtin_amdgcn_exp2f(l2rf * (float)(i + 1));
    const float rg = __builtin_amdgcn_exp2f(l2rf * (float)(N - i));
    const float invz = 1.0f / (1.0f + (2.0f * rr - rl - rg) * inv1mr);

    unsigned short* orow = O + ((size_t)(b * N + i)) * D + h * DH + 4 * hi;
#pragma unroll
    for (int q = 0; q < 4; q++) {
        uint2 o0, o1;
        o0.x = pack2(acc0[4 * q + 0] * invz, acc0[4 * q + 1] * invz);
        o0.y = pack2(acc0[4 * q + 2] * invz, acc0[4 * q + 3] * invz);
        *reinterpret_cast<uint2*>(orow + 8 * q) = o0;
        o1.x = pack2(acc1[4 * q + 0] * invz, acc1[4 * q + 1] * invz);
        o1.y = pack2(acc1[4 * q + 2] * invz, acc1[4 * q + 3] * invz);
        *reinterpret_cast<uint2*>(orow + 32 + 8 * q) = o1;
    }
}

extern "C" void kernel_launch(void* const* d_in, const int* in_sizes, int n_in,
                              void* d_out, int out_size, void* d_ws, size_t ws_size,
                              hipStream_t stream) {
    const float* x      = (const float*)d_in[0];   // (B,N,D)
    const float* W_v    = (const float*)d_in[1];   // (D, 512)
    const float* W_sig  = (const float*)d_in[2];   // (D, H)
    const float* b_sig  = (const float*)d_in[3];   // (H,)
    const float* W_out  = (const float*)d_in[4];   // (512, D)
    const float* b_out  = (const float*)d_in[5];   // (D,)
    float* out = (float*)d_out;

    char* ws = (char*)d_ws;
    unsigned short* Vt   = (unsigned short*)ws;                                // 512*8960*2B = 8.75 MB
    unsigned short* xbf  = (unsigned short*)(ws + (size_t)9  * 1024 * 1024);   // 8 MB (reused as attnOut)
    unsigned short* WvT  = (unsigned short*)(ws + (size_t)17 * 1024 * 1024);   // 512 KB
    unsigned short* WoT  = (unsigned short*)(ws + (size_t)17 * 1024 * 1024 + 524288);
    float*          l2r  = (float*)(ws + (size_t)18 * 1024 * 1024);            // 256 KB
    unsigned short* attnOut = xbf;   // xbf dead after GEMM1

    prep_fused<<<2240, 256, 0, stream>>>(x, W_sig, b_sig, W_v, W_out,
                                         xbf, l2r, WvT, WoT, Vt);

    // 1) Vt = (x @ W_v)^T, bf16, column-padded per batch
    {
        dim3 grid(ROWS / GBN, 512 / GBM);
        gemm_bf16<2><<<grid, 256, 0, stream>>>(WvT, xbf, nullptr, Vt, ROWS, LDV);
    }
    // 2) banded MFMA attention (32x32) -> bf16 row-major O
    attn_mfma<<<B * H * (N / 32) / 4, 256, 0, stream>>>(Vt, l2r, attnOut);
    // 3) out = attnOut @ W_out + b_out  (f32), XCD-swizzled 1D grid
    gemm_bf16<0><<<256, 256, 0, stream>>>(attnOut, WoT, b_out, out, D, D);
}

// Round 12
// 62.789 us; speedup vs baseline: 1.5432x; 1.0594x over previous
//
#include <hip/hip_runtime.h>
#include <hip/hip_bf16.h>

// Problem constants
#define B 4
#define N 2048
#define D 512
#define H 8
#define DH 64
#define ROWS (B * N)        // 8192
#define WIN 64              // r<=0.764 -> r^64 ~ 3e-8
#define LPAD 64             // left col pad in Vt
#define RPAD 128            // right col pad in Vt
#define SEG (LPAD + N + RPAD)   // 2240 cols per batch in Vt
#define LDV (B * SEG)           // 8960 = Vt row length

using bf16x8 = __attribute__((ext_vector_type(8))) short;
using f32x4  = __attribute__((ext_vector_type(4))) float;
using f32x16 = __attribute__((ext_vector_type(16))) float;

static __device__ __forceinline__ unsigned short f2bf(float f) {
    unsigned u = __builtin_bit_cast(unsigned, f);
    u += 0x7fffu + ((u >> 16) & 1u);        // round-to-nearest-even
    return (unsigned short)(u >> 16);
}
static __device__ __forceinline__ unsigned pack2(float a, float b) {
    return (unsigned)f2bf(a) | ((unsigned)f2bf(b) << 16);
}

// ------------- fused prep: x->bf16 + f32 sigma (blocks 0..2047),
//               WvT (2048..2111), WoT (2112..2175), Vt pad zero (2176..2239) ---
__global__ __launch_bounds__(256) void prep_fused(const float* __restrict__ x,
                                                  const float* __restrict__ Ws,
                                                  const float* __restrict__ bs,
                                                  const float* __restrict__ Wv,
                                                  const float* __restrict__ Wo,
                                                  unsigned short* __restrict__ xbf,
                                                  float* __restrict__ l2rbuf,
                                                  unsigned short* __restrict__ WvT,
                                                  unsigned short* __restrict__ WoT,
                                                  unsigned short* __restrict__ Vt) {
    __shared__ float tile[64][65];
    const int bx = blockIdx.x;

    if (bx < 2048) {
        // ---- x convert + f32 sigma (precision-critical: feeds exp chain) ----
        const int wid = threadIdx.x >> 6, lane = threadIdx.x & 63;
        const int row = bx * 4 + wid;
        const float* xr = x + (size_t)row * D + lane * 8;
        const float4 a = *reinterpret_cast<const float4*>(xr);
        const float4 c = *reinterpret_cast<const float4*>(xr + 4);
        float v[8] = {a.x, a.y, a.z, a.w, c.x, c.y, c.z, c.w};

        uint4 o;
        o.x = pack2(v[0], v[1]); o.y = pack2(v[2], v[3]);
        o.z = pack2(v[4], v[5]); o.w = pack2(v[6], v[7]);
        *reinterpret_cast<uint4*>(xbf + (size_t)row * D + lane * 8) = o;

        const float4* Ws4 = reinterpret_cast<const float4*>(Ws);   // (D, 8)
        f32x4 alo = (f32x4)0.0f, ahi = (f32x4)0.0f;
#pragma unroll
        for (int j = 0; j < 8; j++) {
            const int e = lane * 8 + j;
            const float4 wl = Ws4[e * 2], wh = Ws4[e * 2 + 1];
            alo[0] += v[j] * wl.x; alo[1] += v[j] * wl.y; alo[2] += v[j] * wl.z; alo[3] += v[j] * wl.w;
            ahi[0] += v[j] * wh.x; ahi[1] += v[j] * wh.y; ahi[2] += v[j] * wh.z; ahi[3] += v[j] * wh.w;
        }
#pragma unroll
        for (int off = 1; off < 64; off <<= 1) {
#pragma unroll
            for (int c2 = 0; c2 < 4; c2++) {
                alo[c2] += __shfl_xor(alo[c2], off, 64);
                ahi[c2] += __shfl_xor(ahi[c2], off, 64);
            }
        }
        if (lane < 8) {
            const int h = lane;
            const float acc = (h < 4) ? alo[h] : ahi[h - 4];
            const float z = acc + bs[h];
            const float sig = 1.0f / (1.0f + expf(-z));
            const float s = expf(sig) + 1.0f;
            l2rbuf[(size_t)row * H + h] = -1.4426950408889634f / s;
        }
        return;
    }

    if (bx < 2176) {
        // ---- W transpose+convert ----
        const int idx = bx - 2048;
        const bool second = idx >= 64;
        const int id2 = idx & 63;
        const float* src = second ? Wo : Wv;
        unsigned short* dst = second ? WoT : WvT;
        const int n0 = (id2 & 7) * 64, k0 = (id2 >> 3) * 64;
        const int tr = threadIdx.x >> 4, tc = threadIdx.x & 15;
#pragma unroll
        for (int it = 0; it < 4; it++) {
            const int r = it * 16 + tr;
            const float4 v = *reinterpret_cast<const float4*>(&src[(size_t)(k0 + r) * 512 + n0 + tc * 4]);
            tile[r][tc * 4 + 0] = v.x; tile[r][tc * 4 + 1] = v.y;
            tile[r][tc * 4 + 2] = v.z; tile[r][tc * 4 + 3] = v.w;
        }
        __syncthreads();
#pragma unroll
        for (int it = 0; it < 4; it++) {
            const int r = it * 16 + tr;
            ushort4 o;
            o.x = f2bf(tile[tc * 4 + 0][r]); o.y = f2bf(tile[tc * 4 + 1][r]);
            o.z = f2bf(tile[tc * 4 + 2][r]); o.w = f2bf(tile[tc * 4 + 3][r]);
            *reinterpret_cast<ushort4*>(&dst[(size_t)(n0 + r) * 512 + k0 + tc * 4]) = o;
        }
        return;
    }

    // ---- zero pad cols of Vt ----
    {
        const int idx = bx - 2176;   // 0..63
        for (int t = idx * 256 + threadIdx.x; t < 512 * 4 * 24; t += 64 * 256) {
            const int c = t % 24;
            const int bb = (t / 24) & 3;
            const int row = t / 96;
            const int col = (c < 8) ? bb * SEG + c * 8 : bb * SEG + LPAD + N + (c - 8) * 8;
            *reinterpret_cast<uint4*>(Vt + (size_t)row * LDV + col) = uint4{0, 0, 0, 0};
        }
    }
}

// ---------------- bf16 MFMA GEMM, 64x64 tile, GBK=64, double-buffered ---------
// C[M,Nn] = A[M,K=512] @ Bt[Nn,K=512]^T ; 5 blocks/CU co-resident (TLP).
// MODE 0: f32 out + bias, 1D grid 1024 with bijective XCD swizzle (bm=128,bn=8).
// MODE 2: bf16 out into Vt with col remap, 2D grid (bn=128, bm=8).
#define GBK 64
#define GK  512

template <int MODE>
__global__ __launch_bounds__(256) void gemm_bf16(const unsigned short* __restrict__ A,
                                                 const unsigned short* __restrict__ Bt,
                                                 const float* __restrict__ bias,
                                                 void* __restrict__ Cout,
                                                 int ldc) {
    __shared__ unsigned short As[2][64][GBK];   // 8 KB x2
    __shared__ unsigned short Bs[2][64][GBK];   // 8 KB x2 (32 KB total)
    const int tid = threadIdx.x;
    const int lane = tid & 63, wid = tid >> 6;
    const int wr = wid >> 1, wc = wid & 1;      // 2x2 waves: 32x32 each
    int bm, bn;
    if (MODE == 0) {
        // bijective XCD swizzle for grid 1024: each XCD gets 16 bm x 8 bn
        const int xcd = blockIdx.x & 7, idx = blockIdx.x >> 3;
        bm = xcd * 16 + (idx >> 3);
        bn = idx & 7;
    } else {
        bn = blockIdx.x; bm = blockIdx.y;
    }
    const int fr = lane & 15, kg = lane >> 4;

    f32x4 acc[2][2] = {};

    const unsigned short* Ab = A + (size_t)bm * 64 * GK;
    const unsigned short* Bb = Bt + (size_t)bn * 64 * GK;
    const int r32 = tid >> 3, c8 = (tid & 7) * 8;   // 32 rows/pass, 16B chunks

    auto stage = [&](int buf, int k0) {
#pragma unroll
        for (int it = 0; it < 2; it++) {
            const unsigned short* g = Ab + (size_t)(it * 32 + r32) * GK + k0 + c8;
            __builtin_amdgcn_global_load_lds(
                (const __attribute__((address_space(1))) void*)g,
                (__attribute__((address_space(3))) void*)&As[buf][it * 32 + r32][c8], 16, 0, 0);
        }
#pragma unroll
        for (int it = 0; it < 2; it++) {
            const unsigned short* g = Bb + (size_t)(it * 32 + r32) * GK + k0 + c8;
            __builtin_amdgcn_global_load_lds(
                (const __attribute__((address_space(1))) void*)g,
                (__attribute__((address_space(3))) void*)&Bs[buf][it * 32 + r32][c8], 16, 0, 0);
        }
    };

    stage(0, 0);
    __syncthreads();
    int cur = 0;
#pragma unroll
    for (int kt = 0; kt < GK / GBK; kt++) {
        if (kt + 1 < GK / GBK) stage(cur ^ 1, (kt + 1) * GBK);
#pragma unroll
        for (int ks = 0; ks < 2; ks++) {
            bf16x8 af[2], bfr[2];
#pragma unroll
            for (int m = 0; m < 2; m++)
                af[m] = *reinterpret_cast<const bf16x8*>(&As[cur][wr * 32 + m * 16 + fr][ks * 32 + kg * 8]);
#pragma unroll
            for (int n = 0; n < 2; n++)
                bfr[n] = *reinterpret_cast<const bf16x8*>(&Bs[cur][wc * 32 + n * 16 + fr][ks * 32 + kg * 8]);
#pragma unroll
            for (int m = 0; m < 2; m++)
#pragma unroll
                for (int n = 0; n < 2; n++)
                    acc[m][n] = __builtin_amdgcn_mfma_f32_16x16x32_bf16(af[m], bfr[n], acc[m][n], 0, 0, 0);
        }
        __syncthreads();
        cur ^= 1;
    }

#pragma unroll
    for (int n = 0; n < 2; n++) {
        const int col = bn * 64 + wc * 32 + n * 16 + fr;
        const float bv = (MODE == 0 && bias) ? bias[col] : 0.0f;
        const int cp = (MODE == 2) ? ((col >> 11) * SEG + LPAD + (col & 2047)) : col;
#pragma unroll
        for (int m = 0; m < 2; m++) {
            const int row0 = bm * 64 + wr * 32 + m * 16 + kg * 4;
#pragma unroll
            for (int j = 0; j < 4; j++) {
                const int row = row0 + j;
                if (MODE == 0)
                    ((float*)Cout)[(size_t)row * ldc + col] = acc[m][n][j] + bv;
                else
                    ((unsigned short*)Cout)[(size_t)row * ldc + cp] = f2bf(acc[m][n][j]);
            }
        }
    }
}

// ---------------- MFMA banded attention, 32x32x16 -----------------------------
// wave -> (b, h, 32-row i-tile). O^T(64d x 32i) = Vt(64d x 160j) * P^T(160j x 32i)
__global__ __launch_bounds__(256) void attn_mfma(const unsigned short* __restrict__ Vt,
                                                 const float* __restrict__ l2rbuf,
                                                 unsigned short* __restrict__ O) {
    const int wid = threadIdx.x >> 6;
    const int lane = threadIdx.x & 63;
    const int il = lane & 31, hi = lane >> 5;
    const int gi = blockIdx.x * 4 + wid;       // over (b,h,iblk)
    const int iblk = gi & 63;                  // N/32 = 64
    const int bh = gi >> 6;
    const int h = bh & 7;
    const int b = bh >> 3;
    const int i0 = iblk * 32;

    const int i = i0 + il;                     // this lane's query row (C col)
    const float l2rf = l2rbuf[((size_t)(b * N + i)) * H + h];

    const unsigned short* Va = Vt + (size_t)(h * DH + il) * LDV + (size_t)b * SEG + i0 + hi * 8;

    f32x16 acc0 = (f32x16)0.0f, acc1 = (f32x16)0.0f;
    __builtin_amdgcn_s_setprio(1);
#pragma unroll
    for (int ks = 0; ks < 10; ks++) {
        const float jb = (float)(ks * 16 + hi * 8 - WIN - il);
        float wv[8];
#pragma unroll
        for (int e = 0; e < 8; e++)
            wv[e] = __builtin_amdgcn_exp2f(l2rf * __builtin_fabsf(jb + (float)e));
        uint4 uw;
        uw.x = pack2(wv[0], wv[1]); uw.y = pack2(wv[2], wv[3]);
        uw.z = pack2(wv[4], wv[5]); uw.w = pack2(wv[6], wv[7]);
        const bf16x8 pB = __builtin_bit_cast(bf16x8, uw);
        const bf16x8 a0 = *reinterpret_cast<const bf16x8*>(Va + (size_t)ks * 16);
        const bf16x8 a1 = *reinterpret_cast<const bf16x8*>(Va + (size_t)32 * LDV + (size_t)ks * 16);
        acc0 = __builtin_amdgcn_mfma_f32_32x32x16_bf16(a0, pB, acc0, 0, 0, 0);
        acc1 = __builtin_amdgcn_mfma_f32_32x32x16_bf16(a1, pB, acc1, 0, 0, 0);
    }
    __builtin_amdgcn_s_setprio(0);

    const float rr = __builtin_amdgcn_exp2f(l2rf);
    const float inv1mr = 1.0f / (1.0f - rr);
    const float rl = __builtin_amdgcn_exp2f(l2rf * (float)(i + 1));
    const float rg = __builtin_amdgcn_exp2f(l2rf * (float)(N - i));
    const float invz = 1.0f / (1.0f + (2.0f * rr - rl - rg) * inv1mr);

    unsigned short* orow = O + ((size_t)(b * N + i)) * D + h * DH + 4 * hi;
#pragma unroll
    for (int q = 0; q < 4; q++) {
        uint2 o0, o1;
        o0.x = pack2(acc0[4 * q + 0] * invz, acc0[4 * q + 1] * invz);
        o0.y = pack2(acc0[4 * q + 2] * invz, acc0[4 * q + 3] * invz);
        *reinterpret_cast<uint2*>(orow + 8 * q) = o0;
        o1.x = pack2(acc1[4 * q + 0] * invz, acc1[4 * q + 1] * invz);
        o1.y = pack2(acc1[4 * q + 2] * invz, acc1[4 * q + 3] * invz);
        *reinterpret_cast<uint2*>(orow + 32 + 8 * q) = o1;
    }
}

extern "C" void kernel_launch(void* const* d_in, const int* in_sizes, int n_in,
                              void* d_out, int out_size, void* d_ws, size_t ws_size,
                              hipStream_t stream) {
    const float* x      = (const float*)d_in[0];   // (B,N,D)
    const float* W_v    = (const float*)d_in[1];   // (D, 512)
    const float* W_sig  = (const float*)d_in[2];   // (D, H)
    const float* b_sig  = (const float*)d_in[3];   // (H,)
    const float* W_out  = (const float*)d_in[4];   // (512, D)
    const float* b_out  = (const float*)d_in[5];   // (D,)
    float* out = (float*)d_out;

    char* ws = (char*)d_ws;
    unsigned short* Vt   = (unsigned short*)ws;                                // 8.75 MB
    unsigned short* xbf  = (unsigned short*)(ws + (size_t)9  * 1024 * 1024);   // 8 MB (reused as attnOut)
    unsigned short* WvT  = (unsigned short*)(ws + (size_t)17 * 1024 * 1024);   // 512 KB
    unsigned short* WoT  = (unsigned short*)(ws + (size_t)17 * 1024 * 1024 + 524288);
    float*          l2r  = (float*)(ws + (size_t)18 * 1024 * 1024);            // 256 KB
    unsigned short* attnOut = xbf;   // xbf dead after GEMM1

    prep_fused<<<2240, 256, 0, stream>>>(x, W_sig, b_sig, W_v, W_out,
                                         xbf, l2r, WvT, WoT, Vt);

    // 1) Vt = (x @ W_v)^T, bf16, column-padded per batch
    {
        dim3 grid(128, 8);
        gemm_bf16<2><<<grid, 256, 0, stream>>>(WvT, xbf, nullptr, Vt, LDV);
    }
    // 2) banded MFMA attention (32x32) -> bf16 row-major O
    attn_mfma<<<B * H * (N / 32) / 4, 256, 0, stream>>>(Vt, l2r, attnOut);
    // 3) out = attnOut @ W_out + b_out (f32), 1D grid 1024, XCD-swizzled
    gemm_bf16<0><<<1024, 256, 0, stream>>>(attnOut, WoT, b_out, out, D);
}

// Round 13
// 61.667 us; speedup vs baseline: 1.5713x; 1.0182x over previous
//
#include <hip/hip_runtime.h>
#include <hip/hip_bf16.h>

// Problem constants
#define B 4
#define N 2048
#define D 512
#define H 8
#define DH 64
#define ROWS (B * N)        // 8192
#define WIN 64              // Vt pad sizing (layout kept from R12)
#define AWIN 48             // attn band half-width; r<=2^-0.388 -> tail < 5e-5
#define LPAD 64             // left col pad in Vt
#define RPAD 128            // right col pad in Vt
#define SEG (LPAD + N + RPAD)   // 2240 cols per batch in Vt
#define LDV (B * SEG)           // 8960 = Vt row length

using bf16x8 = __attribute__((ext_vector_type(8))) short;
using f32x4  = __attribute__((ext_vector_type(4))) float;
using f32x16 = __attribute__((ext_vector_type(16))) float;

static __device__ __forceinline__ unsigned short f2bf(float f) {
    unsigned u = __builtin_bit_cast(unsigned, f);
    u += 0x7fffu + ((u >> 16) & 1u);        // round-to-nearest-even
    return (unsigned short)(u >> 16);
}
static __device__ __forceinline__ unsigned pack2(float a, float b) {
    return (unsigned)f2bf(a) | ((unsigned)f2bf(b) << 16);
}

// ------------- fused prep: x->bf16 + f32 sigma (blocks 0..2047),
//               WvT (2048..2111), WoT (2112..2175), Vt pad zero (2176..2239) ---
__global__ __launch_bounds__(256) void prep_fused(const float* __restrict__ x,
                                                  const float* __restrict__ Ws,
                                                  const float* __restrict__ bs,
                                                  const float* __restrict__ Wv,
                                                  const float* __restrict__ Wo,
                                                  unsigned short* __restrict__ xbf,
                                                  float* __restrict__ l2rbuf,
                                                  unsigned short* __restrict__ WvT,
                                                  unsigned short* __restrict__ WoT,
                                                  unsigned short* __restrict__ Vt) {
    __shared__ float tile[64][65];
    const int bx = blockIdx.x;

    if (bx < 2048) {
        // ---- x convert + f32 sigma (precision-critical: feeds exp chain) ----
        const int wid = threadIdx.x >> 6, lane = threadIdx.x & 63;
        const int row = bx * 4 + wid;
        const float* xr = x + (size_t)row * D + lane * 8;
        const float4 a = *reinterpret_cast<const float4*>(xr);
        const float4 c = *reinterpret_cast<const float4*>(xr + 4);
        float v[8] = {a.x, a.y, a.z, a.w, c.x, c.y, c.z, c.w};

        uint4 o;
        o.x = pack2(v[0], v[1]); o.y = pack2(v[2], v[3]);
        o.z = pack2(v[4], v[5]); o.w = pack2(v[6], v[7]);
        *reinterpret_cast<uint4*>(xbf + (size_t)row * D + lane * 8) = o;

        const float4* Ws4 = reinterpret_cast<const float4*>(Ws);   // (D, 8)
        f32x4 alo = (f32x4)0.0f, ahi = (f32x4)0.0f;
#pragma unroll
        for (int j = 0; j < 8; j++) {
            const int e = lane * 8 + j;
            const float4 wl = Ws4[e * 2], wh = Ws4[e * 2 + 1];
            alo[0] += v[j] * wl.x; alo[1] += v[j] * wl.y; alo[2] += v[j] * wl.z; alo[3] += v[j] * wl.w;
            ahi[0] += v[j] * wh.x; ahi[1] += v[j] * wh.y; ahi[2] += v[j] * wh.z; ahi[3] += v[j] * wh.w;
        }
#pragma unroll
        for (int off = 1; off < 64; off <<= 1) {
#pragma unroll
            for (int c2 = 0; c2 < 4; c2++) {
                alo[c2] += __shfl_xor(alo[c2], off, 64);
                ahi[c2] += __shfl_xor(ahi[c2], off, 64);
            }
        }
        if (lane < 8) {
            const int h = lane;
            const float acc = (h < 4) ? alo[h] : ahi[h - 4];
            const float z = acc + bs[h];
            const float sig = 1.0f / (1.0f + expf(-z));
            const float s = expf(sig) + 1.0f;
            l2rbuf[(size_t)row * H + h] = -1.4426950408889634f / s;
        }
        return;
    }

    if (bx < 2176) {
        // ---- W transpose+convert ----
        const int idx = bx - 2048;
        const bool second = idx >= 64;
        const int id2 = idx & 63;
        const float* src = second ? Wo : Wv;
        unsigned short* dst = second ? WoT : WvT;
        const int n0 = (id2 & 7) * 64, k0 = (id2 >> 3) * 64;
        const int tr = threadIdx.x >> 4, tc = threadIdx.x & 15;
#pragma unroll
        for (int it = 0; it < 4; it++) {
            const int r = it * 16 + tr;
            const float4 v = *reinterpret_cast<const float4*>(&src[(size_t)(k0 + r) * 512 + n0 + tc * 4]);
            tile[r][tc * 4 + 0] = v.x; tile[r][tc * 4 + 1] = v.y;
            tile[r][tc * 4 + 2] = v.z; tile[r][tc * 4 + 3] = v.w;
        }
        __syncthreads();
#pragma unroll
        for (int it = 0; it < 4; it++) {
            const int r = it * 16 + tr;
            ushort4 o;
            o.x = f2bf(tile[tc * 4 + 0][r]); o.y = f2bf(tile[tc * 4 + 1][r]);
            o.z = f2bf(tile[tc * 4 + 2][r]); o.w = f2bf(tile[tc * 4 + 3][r]);
            *reinterpret_cast<ushort4*>(&dst[(size_t)(n0 + r) * 512 + k0 + tc * 4]) = o;
        }
        return;
    }

    // ---- zero pad cols of Vt ----
    {
        const int idx = bx - 2176;   // 0..63
        for (int t = idx * 256 + threadIdx.x; t < 512 * 4 * 24; t += 64 * 256) {
            const int c = t % 24;
            const int bb = (t / 24) & 3;
            const int row = t / 96;
            const int col = (c < 8) ? bb * SEG + c * 8 : bb * SEG + LPAD + N + (c - 8) * 8;
            *reinterpret_cast<uint4*>(Vt + (size_t)row * LDV + col) = uint4{0, 0, 0, 0};
        }
    }
}

// ---------------- bf16 MFMA GEMM, 64x64 tile, GBK=64, double-buffered ---------
// C[M,Nn] = A[M,K=512] @ Bt[Nn,K=512]^T ; 4-5 blocks/CU co-resident (TLP).
// MODE 0: f32 out + bias, 1D grid 1024 with bijective XCD swizzle (bm=128,bn=8).
// MODE 2: bf16 out into Vt with col remap, 2D grid (bn=128, bm=8).
#define GBK 64
#define GK  512

template <int MODE>
__global__ __launch_bounds__(256) void gemm_bf16(const unsigned short* __restrict__ A,
                                                 const unsigned short* __restrict__ Bt,
                                                 const float* __restrict__ bias,
                                                 void* __restrict__ Cout,
                                                 int ldc) {
    __shared__ unsigned short As[2][64][GBK];   // 8 KB x2
    __shared__ unsigned short Bs[2][64][GBK];   // 8 KB x2 (32 KB total)
    const int tid = threadIdx.x;
    const int lane = tid & 63, wid = tid >> 6;
    const int wr = wid >> 1, wc = wid & 1;      // 2x2 waves: 32x32 each
    int bm, bn;
    if (MODE == 0) {
        // bijective XCD swizzle for grid 1024: each XCD gets 16 bm x 8 bn
        const int xcd = blockIdx.x & 7, idx = blockIdx.x >> 3;
        bm = xcd * 16 + (idx >> 3);
        bn = idx & 7;
    } else {
        bn = blockIdx.x; bm = blockIdx.y;
    }
    const int fr = lane & 15, kg = lane >> 4;

    f32x4 acc[2][2] = {};

    const unsigned short* Ab = A + (size_t)bm * 64 * GK;
    const unsigned short* Bb = Bt + (size_t)bn * 64 * GK;
    const int r32 = tid >> 3, c8 = (tid & 7) * 8;   // 32 rows/pass, 16B chunks

    auto stage = [&](int buf, int k0) {
#pragma unroll
        for (int it = 0; it < 2; it++) {
            const unsigned short* g = Ab + (size_t)(it * 32 + r32) * GK + k0 + c8;
            __builtin_amdgcn_global_load_lds(
                (const __attribute__((address_space(1))) void*)g,
                (__attribute__((address_space(3))) void*)&As[buf][it * 32 + r32][c8], 16, 0, 0);
        }
#pragma unroll
        for (int it = 0; it < 2; it++) {
            const unsigned short* g = Bb + (size_t)(it * 32 + r32) * GK + k0 + c8;
            __builtin_amdgcn_global_load_lds(
                (const __attribute__((address_space(1))) void*)g,
                (__attribute__((address_space(3))) void*)&Bs[buf][it * 32 + r32][c8], 16, 0, 0);
        }
    };

    stage(0, 0);
    __syncthreads();
    int cur = 0;
#pragma unroll
    for (int kt = 0; kt < GK / GBK; kt++) {
        if (kt + 1 < GK / GBK) stage(cur ^ 1, (kt + 1) * GBK);
#pragma unroll
        for (int ks = 0; ks < 2; ks++) {
            bf16x8 af[2], bfr[2];
#pragma unroll
            for (int m = 0; m < 2; m++)
                af[m] = *reinterpret_cast<const bf16x8*>(&As[cur][wr * 32 + m * 16 + fr][ks * 32 + kg * 8]);
#pragma unroll
            for (int n = 0; n < 2; n++)
                bfr[n] = *reinterpret_cast<const bf16x8*>(&Bs[cur][wc * 32 + n * 16 + fr][ks * 32 + kg * 8]);
#pragma unroll
            for (int m = 0; m < 2; m++)
#pragma unroll
                for (int n = 0; n < 2; n++)
                    acc[m][n] = __builtin_amdgcn_mfma_f32_16x16x32_bf16(af[m], bfr[n], acc[m][n], 0, 0, 0);
        }
        __syncthreads();
        cur ^= 1;
    }

#pragma unroll
    for (int n = 0; n < 2; n++) {
        const int col = bn * 64 + wc * 32 + n * 16 + fr;
        const float bv = (MODE == 0 && bias) ? bias[col] : 0.0f;
        const int cp = (MODE == 2) ? ((col >> 11) * SEG + LPAD + (col & 2047)) : col;
#pragma unroll
        for (int m = 0; m < 2; m++) {
            const int row0 = bm * 64 + wr * 32 + m * 16 + kg * 4;
#pragma unroll
            for (int j = 0; j < 4; j++) {
                const int row = row0 + j;
                if (MODE == 0)
                    ((float*)Cout)[(size_t)row * ldc + col] = acc[m][n][j] + bv;
                else
                    ((unsigned short*)Cout)[(size_t)row * ldc + cp] = f2bf(acc[m][n][j]);
            }
        }
    }
}

// ---------------- MFMA banded attention, 32x32x16, d-split --------------------
// wave -> (b, h, 32-row i-tile, 32-d half). 4096 waves, grid 1024 XCD-swizzled.
// O^T(32d x 32i) = Vt(32d x 128j) * P^T(128j x 32i), band j in [i0-48, i0+80).
__global__ __launch_bounds__(256) void attn_mfma(const unsigned short* __restrict__ Vt,
                                                 const float* __restrict__ l2rbuf,
                                                 unsigned short* __restrict__ O) {
    const int wid = threadIdx.x >> 6;
    const int lane = threadIdx.x & 63;
    const int il = lane & 31, hi = lane >> 5;
    // bijective XCD swizzle: 1024 blocks -> each XCD gets 128 consecutive ids
    const int sbid = (blockIdx.x & 7) * 128 + (blockIdx.x >> 3);
    const int gi = sbid * 4 + wid;             // over (b,h,iblk,dhalf), 4096
    const int dhalf = gi & 1;
    const int iblk = (gi >> 1) & 63;           // N/32 = 64
    const int bh = gi >> 7;
    const int h = bh & 7;
    const int b = bh >> 3;
    const int i0 = iblk * 32;

    const int i = i0 + il;                     // this lane's query row (C col)
    const float l2rf = l2rbuf[((size_t)(b * N + i)) * H + h];

    // A-frag base: Vt row (h*64 + dhalf*32 + il), band start col i0 - AWIN
    const unsigned short* Va = Vt + (size_t)(h * DH + dhalf * 32 + il) * LDV
                              + (size_t)b * SEG + (LPAD - AWIN) + i0 + hi * 8;

    f32x16 acc = (f32x16)0.0f;
    __builtin_amdgcn_s_setprio(1);
#pragma unroll
    for (int ks = 0; ks < 8; ks++) {
        // B-frag: 8 weights, j - i = ks*16 + hi*8 + e - AWIN - il
        const float jb = (float)(ks * 16 + hi * 8 - AWIN - il);
        float wv[8];
#pragma unroll
        for (int e = 0; e < 8; e++)
            wv[e] = __builtin_amdgcn_exp2f(l2rf * __builtin_fabsf(jb + (float)e));
        uint4 uw;
        uw.x = pack2(wv[0], wv[1]); uw.y = pack2(wv[2], wv[3]);
        uw.z = pack2(wv[4], wv[5]); uw.w = pack2(wv[6], wv[7]);
        const bf16x8 pB = __builtin_bit_cast(bf16x8, uw);
        const bf16x8 a0 = *reinterpret_cast<const bf16x8*>(Va + (size_t)ks * 16);
        acc = __builtin_amdgcn_mfma_f32_32x32x16_bf16(a0, pB, acc, 0, 0, 0);
    }
    __builtin_amdgcn_s_setprio(0);

    // closed-form softmax denominator (exact, full-N sum)
    const float rr = __builtin_amdgcn_exp2f(l2rf);
    const float inv1mr = 1.0f / (1.0f - rr);
    const float rl = __builtin_amdgcn_exp2f(l2rf * (float)(i + 1));
    const float rg = __builtin_amdgcn_exp2f(l2rf * (float)(N - i));
    const float invz = 1.0f / (1.0f + (2.0f * rr - rl - rg) * inv1mr);

    // store: d = dhalf*32 + 4*hi + 8*q + (reg&3)
    unsigned short* orow = O + ((size_t)(b * N + i)) * D + h * DH + dhalf * 32 + 4 * hi;
#pragma unroll
    for (int q = 0; q < 4; q++) {
        uint2 o0;
        o0.x = pack2(acc[4 * q + 0] * invz, acc[4 * q + 1] * invz);
        o0.y = pack2(acc[4 * q + 2] * invz, acc[4 * q + 3] * invz);
        *reinterpret_cast<uint2*>(orow + 8 * q) = o0;
    }
}

extern "C" void kernel_launch(void* const* d_in, const int* in_sizes, int n_in,
                              void* d_out, int out_size, void* d_ws, size_t ws_size,
                              hipStream_t stream) {
    const float* x      = (const float*)d_in[0];   // (B,N,D)
    const float* W_v    = (const float*)d_in[1];   // (D, 512)
    const float* W_sig  = (const float*)d_in[2];   // (D, H)
    const float* b_sig  = (const float*)d_in[3];   // (H,)
    const float* W_out  = (const float*)d_in[4];   // (512, D)
    const float* b_out  = (const float*)d_in[5];   // (D,)
    float* out = (float*)d_out;

    char* ws = (char*)d_ws;
    unsigned short* Vt   = (unsigned short*)ws;                                // 8.75 MB
    unsigned short* xbf  = (unsigned short*)(ws + (size_t)9  * 1024 * 1024);   // 8 MB (reused as attnOut)
    unsigned short* WvT  = (unsigned short*)(ws + (size_t)17 * 1024 * 1024);   // 512 KB
    unsigned short* WoT  = (unsigned short*)(ws + (size_t)17 * 1024 * 1024 + 524288);
    float*          l2r  = (float*)(ws + (size_t)18 * 1024 * 1024);            // 256 KB
    unsigned short* attnOut = xbf;   // xbf dead after GEMM1

    prep_fused<<<2240, 256, 0, stream>>>(x, W_sig, b_sig, W_v, W_out,
                                         xbf, l2r, WvT, WoT, Vt);

    // 1) Vt = (x @ W_v)^T, bf16, column-padded per batch
    {
        dim3 grid(128, 8);
        gemm_bf16<2><<<grid, 256, 0, stream>>>(WvT, xbf, nullptr, Vt, LDV);
    }
    // 2) banded MFMA attention (32x32, d-split) -> bf16 row-major O
    attn_mfma<<<1024, 256, 0, stream>>>(Vt, l2r, attnOut);
    // 3) out = attnOut @ W_out + b_out (f32), 1D grid 1024, XCD-swizzled
    gemm_bf16<0><<<1024, 256, 0, stream>>>(attnOut, WoT, b_out, out, D);
}

// Round 14
// 57.013 us; speedup vs baseline: 1.6995x; 1.0816x over previous
//
#include <hip/hip_runtime.h>
#include <hip/hip_bf16.h>

// Problem constants
#define B 4
#define N 2048
#define D 512
#define H 8
#define DH 64
#define ROWS (B * N)        // 8192
#define WIN 64              // Vt pad sizing
#define AWIN 48             // attn band half-width; tail < 5e-5
#define LPAD 64             // left col pad in Vt
#define RPAD 128            // right col pad in Vt
#define SEG (LPAD + N + RPAD)   // 2240 cols per batch in Vt
#define LDV (B * SEG)           // 8960 = Vt row length

using bf16x8 = __attribute__((ext_vector_type(8))) short;
using f32x4  = __attribute__((ext_vector_type(4))) float;
using f32x16 = __attribute__((ext_vector_type(16))) float;

static __device__ __forceinline__ unsigned short f2bf(float f) {
    unsigned u = __builtin_bit_cast(unsigned, f);
    u += 0x7fffu + ((u >> 16) & 1u);        // round-to-nearest-even
    return (unsigned short)(u >> 16);
}
static __device__ __forceinline__ unsigned pack2(float a, float b) {
    return (unsigned)f2bf(a) | ((unsigned)f2bf(b) << 16);
}

// ------------- fused prep: x->bf16 + f32 sigma (blocks 0..2047),
//               WvT (2048..2111), WoT (2112..2175), Vt pad zero (2176..2239) ---
__global__ __launch_bounds__(256) void prep_fused(const float* __restrict__ x,
                                                  const float* __restrict__ Ws,
                                                  const float* __restrict__ bs,
                                                  const float* __restrict__ Wv,
                                                  const float* __restrict__ Wo,
                                                  unsigned short* __restrict__ xbf,
                                                  float* __restrict__ l2rbuf,
                                                  unsigned short* __restrict__ WvT,
                                                  unsigned short* __restrict__ WoT,
                                                  unsigned short* __restrict__ Vt) {
    __shared__ float tile[64][65];
    const int bx = blockIdx.x;

    if (bx < 2048) {
        // ---- x convert + f32 sigma (precision-critical: feeds exp chain) ----
        const int wid = threadIdx.x >> 6, lane = threadIdx.x & 63;
        const int row = bx * 4 + wid;
        const float* xr = x + (size_t)row * D + lane * 8;
        const float4 a = *reinterpret_cast<const float4*>(xr);
        const float4 c = *reinterpret_cast<const float4*>(xr + 4);
        float v[8] = {a.x, a.y, a.z, a.w, c.x, c.y, c.z, c.w};

        uint4 o;
        o.x = pack2(v[0], v[1]); o.y = pack2(v[2], v[3]);
        o.z = pack2(v[4], v[5]); o.w = pack2(v[6], v[7]);
        *reinterpret_cast<uint4*>(xbf + (size_t)row * D + lane * 8) = o;

        const float4* Ws4 = reinterpret_cast<const float4*>(Ws);   // (D, 8)
        f32x4 alo = (f32x4)0.0f, ahi = (f32x4)0.0f;
#pragma unroll
        for (int j = 0; j < 8; j++) {
            const int e = lane * 8 + j;
            const float4 wl = Ws4[e * 2], wh = Ws4[e * 2 + 1];
            alo[0] += v[j] * wl.x; alo[1] += v[j] * wl.y; alo[2] += v[j] * wl.z; alo[3] += v[j] * wl.w;
            ahi[0] += v[j] * wh.x; ahi[1] += v[j] * wh.y; ahi[2] += v[j] * wh.z; ahi[3] += v[j] * wh.w;
        }
#pragma unroll
        for (int off = 1; off < 64; off <<= 1) {
#pragma unroll
            for (int c2 = 0; c2 < 4; c2++) {
                alo[c2] += __shfl_xor(alo[c2], off, 64);
                ahi[c2] += __shfl_xor(ahi[c2], off, 64);
            }
        }
        if (lane < 8) {
            const int h = lane;
            const float acc = (h < 4) ? alo[h] : ahi[h - 4];
            const float z = acc + bs[h];
            const float sig = 1.0f / (1.0f + expf(-z));
            const float s = expf(sig) + 1.0f;
            l2rbuf[(size_t)row * H + h] = -1.4426950408889634f / s;
        }
        return;
    }

    if (bx < 2176) {
        // ---- W transpose+convert ----
        const int idx = bx - 2048;
        const bool second = idx >= 64;
        const int id2 = idx & 63;
        const float* src = second ? Wo : Wv;
        unsigned short* dst = second ? WoT : WvT;
        const int n0 = (id2 & 7) * 64, k0 = (id2 >> 3) * 64;
        const int tr = threadIdx.x >> 4, tc = threadIdx.x & 15;
#pragma unroll
        for (int it = 0; it < 4; it++) {
            const int r = it * 16 + tr;
            const float4 v = *reinterpret_cast<const float4*>(&src[(size_t)(k0 + r) * 512 + n0 + tc * 4]);
            tile[r][tc * 4 + 0] = v.x; tile[r][tc * 4 + 1] = v.y;
            tile[r][tc * 4 + 2] = v.z; tile[r][tc * 4 + 3] = v.w;
        }
        __syncthreads();
#pragma unroll
        for (int it = 0; it < 4; it++) {
            const int r = it * 16 + tr;
            ushort4 o;
            o.x = f2bf(tile[tc * 4 + 0][r]); o.y = f2bf(tile[tc * 4 + 1][r]);
            o.z = f2bf(tile[tc * 4 + 2][r]); o.w = f2bf(tile[tc * 4 + 3][r]);
            *reinterpret_cast<ushort4*>(&dst[(size_t)(n0 + r) * 512 + k0 + tc * 4]) = o;
        }
        return;
    }

    // ---- zero pad cols of Vt ----
    {
        const int idx = bx - 2176;   // 0..63
        for (int t = idx * 256 + threadIdx.x; t < 512 * 4 * 24; t += 64 * 256) {
            const int c = t % 24;
            const int bb = (t / 24) & 3;
            const int row = t / 96;
            const int col = (c < 8) ? bb * SEG + c * 8 : bb * SEG + LPAD + N + (c - 8) * 8;
            *reinterpret_cast<uint4*>(Vt + (size_t)row * LDV + col) = uint4{0, 0, 0, 0};
        }
    }
}

// ---------------- bf16 MFMA GEMM, 64x64 tile, GBK=64, double-buffered ---------
// LDS XOR-swizzle (rule #21): linear LDS dest, pre-swizzled GLOBAL source chunk
// (ch ^ (row&7)), and the same XOR applied on the ds_read col. Breaks the
// 128-byte-row 16-way bank conflict on fragment reads.
// MODE 0: f32 out + bias, 1D grid 1024 with bijective XCD swizzle.
// MODE 2: bf16 out into Vt with col remap, 2D grid (bn=128, bm=8).
#define GBK 64
#define GK  512

template <int MODE>
__global__ __launch_bounds__(256) void gemm_bf16(const unsigned short* __restrict__ A,
                                                 const unsigned short* __restrict__ Bt,
                                                 const float* __restrict__ bias,
                                                 void* __restrict__ Cout,
                                                 int ldc) {
    __shared__ unsigned short As[2][64][GBK];   // 8 KB x2
    __shared__ unsigned short Bs[2][64][GBK];   // 8 KB x2 (32 KB total)
    const int tid = threadIdx.x;
    const int lane = tid & 63, wid = tid >> 6;
    const int wr = wid >> 1, wc = wid & 1;      // 2x2 waves: 32x32 each
    int bm, bn;
    if (MODE == 0) {
        const int xcd = blockIdx.x & 7, idx = blockIdx.x >> 3;
        bm = xcd * 16 + (idx >> 3);
        bn = idx & 7;
    } else {
        bn = blockIdx.x; bm = blockIdx.y;
    }
    const int fr = lane & 15, kg = lane >> 4;

    f32x4 acc[2][2] = {};

    const unsigned short* Ab = A + (size_t)bm * 64 * GK;
    const unsigned short* Bb = Bt + (size_t)bn * 64 * GK;
    const int r32 = tid >> 3, ch = tid & 7;     // 32 rows/pass, chunk 0..7

    auto stage = [&](int buf, int k0) {
#pragma unroll
        for (int it = 0; it < 2; it++) {
            const int row = it * 32 + r32;
            const int gch = ch ^ (row & 7);     // pre-swizzled global source
            const unsigned short* g = Ab + (size_t)row * GK + k0 + gch * 8;
            __builtin_amdgcn_global_load_lds(
                (const __attribute__((address_space(1))) void*)g,
                (__attribute__((address_space(3))) void*)&As[buf][row][ch * 8], 16, 0, 0);
        }
#pragma unroll
        for (int it = 0; it < 2; it++) {
            const int row = it * 32 + r32;
            const int gch = ch ^ (row & 7);
            const unsigned short* g = Bb + (size_t)row * GK + k0 + gch * 8;
            __builtin_amdgcn_global_load_lds(
                (const __attribute__((address_space(1))) void*)g,
                (__attribute__((address_space(3))) void*)&Bs[buf][row][ch * 8], 16, 0, 0);
        }
    };

    stage(0, 0);
    __syncthreads();
    int cur = 0;
#pragma unroll
    for (int kt = 0; kt < GK / GBK; kt++) {
        if (kt + 1 < GK / GBK) stage(cur ^ 1, (kt + 1) * GBK);
#pragma unroll
        for (int ks = 0; ks < 2; ks++) {
            bf16x8 af[2], bfr[2];
#pragma unroll
            for (int m = 0; m < 2; m++) {
                const int arow = wr * 32 + m * 16 + fr;
                const int rch = (ks * 4 + kg) ^ (arow & 7);   // swizzled read col
                af[m] = *reinterpret_cast<const bf16x8*>(&As[cur][arow][rch * 8]);
            }
#pragma unroll
            for (int n = 0; n < 2; n++) {
                const int brow = wc * 32 + n * 16 + fr;
                const int rch = (ks * 4 + kg) ^ (brow & 7);
                bfr[n] = *reinterpret_cast<const bf16x8*>(&Bs[cur][brow][rch * 8]);
            }
#pragma unroll
            for (int m = 0; m < 2; m++)
#pragma unroll
                for (int n = 0; n < 2; n++)
                    acc[m][n] = __builtin_amdgcn_mfma_f32_16x16x32_bf16(af[m], bfr[n], acc[m][n], 0, 0, 0);
        }
        __syncthreads();
        cur ^= 1;
    }

#pragma unroll
    for (int n = 0; n < 2; n++) {
        const int col = bn * 64 + wc * 32 + n * 16 + fr;
        const float bv = (MODE == 0 && bias) ? bias[col] : 0.0f;
        const int cp = (MODE == 2) ? ((col >> 11) * SEG + LPAD + (col & 2047)) : col;
#pragma unroll
        for (int m = 0; m < 2; m++) {
            const int row0 = bm * 64 + wr * 32 + m * 16 + kg * 4;
#pragma unroll
            for (int j = 0; j < 4; j++) {
                const int row = row0 + j;
                if (MODE == 0)
                    ((float*)Cout)[(size_t)row * ldc + col] = acc[m][n][j] + bv;
                else
                    ((unsigned short*)Cout)[(size_t)row * ldc + cp] = f2bf(acc[m][n][j]);
            }
        }
    }
}

// ---------------- MFMA banded attention, 32x32x16, d-split --------------------
// wave -> (b, h, 32-row i-tile, 32-d half). 4096 waves, grid 1024 XCD-swizzled.
__global__ __launch_bounds__(256) void attn_mfma(const unsigned short* __restrict__ Vt,
                                                 const float* __restrict__ l2rbuf,
                                                 unsigned short* __restrict__ O) {
    const int wid = threadIdx.x >> 6;
    const int lane = threadIdx.x & 63;
    const int il = lane & 31, hi = lane >> 5;
    const int sbid = (blockIdx.x & 7) * 128 + (blockIdx.x >> 3);
    const int gi = sbid * 4 + wid;             // over (b,h,iblk,dhalf), 4096
    const int dhalf = gi & 1;
    const int iblk = (gi >> 1) & 63;           // N/32 = 64
    const int bh = gi >> 7;
    const int h = bh & 7;
    const int b = bh >> 3;
    const int i0 = iblk * 32;

    const int i = i0 + il;                     // this lane's query row (C col)
    const float l2rf = l2rbuf[((size_t)(b * N + i)) * H + h];

    const unsigned short* Va = Vt + (size_t)(h * DH + dhalf * 32 + il) * LDV
                              + (size_t)b * SEG + (LPAD - AWIN) + i0 + hi * 8;

    f32x16 acc = (f32x16)0.0f;
    __builtin_amdgcn_s_setprio(1);
#pragma unroll
    for (int ks = 0; ks < 8; ks++) {
        const float jb = (float)(ks * 16 + hi * 8 - AWIN - il);
        float wv[8];
#pragma unroll
        for (int e = 0; e < 8; e++)
            wv[e] = __builtin_amdgcn_exp2f(l2rf * __builtin_fabsf(jb + (float)e));
        uint4 uw;
        uw.x = pack2(wv[0], wv[1]); uw.y = pack2(wv[2], wv[3]);
        uw.z = pack2(wv[4], wv[5]); uw.w = pack2(wv[6], wv[7]);
        const bf16x8 pB = __builtin_bit_cast(bf16x8, uw);
        const bf16x8 a0 = *reinterpret_cast<const bf16x8*>(Va + (size_t)ks * 16);
        acc = __builtin_amdgcn_mfma_f32_32x32x16_bf16(a0, pB, acc, 0, 0, 0);
    }
    __builtin_amdgcn_s_setprio(0);

    const float rr = __builtin_amdgcn_exp2f(l2rf);
    const float inv1mr = 1.0f / (1.0f - rr);
    const float rl = __builtin_amdgcn_exp2f(l2rf * (float)(i + 1));
    const float rg = __builtin_amdgcn_exp2f(l2rf * (float)(N - i));
    const float invz = 1.0f / (1.0f + (2.0f * rr - rl - rg) * inv1mr);

    unsigned short* orow = O + ((size_t)(b * N + i)) * D + h * DH + dhalf * 32 + 4 * hi;
#pragma unroll
    for (int q = 0; q < 4; q++) {
        uint2 o0;
        o0.x = pack2(acc[4 * q + 0] * invz, acc[4 * q + 1] * invz);
        o0.y = pack2(acc[4 * q + 2] * invz, acc[4 * q + 3] * invz);
        *reinterpret_cast<uint2*>(orow + 8 * q) = o0;
    }
}

extern "C" void kernel_launch(void* const* d_in, const int* in_sizes, int n_in,
                              void* d_out, int out_size, void* d_ws, size_t ws_size,
                              hipStream_t stream) {
    const float* x      = (const float*)d_in[0];   // (B,N,D)
    const float* W_v    = (const float*)d_in[1];   // (D, 512)
    const float* W_sig  = (const float*)d_in[2];   // (D, H)
    const float* b_sig  = (const float*)d_in[3];   // (H,)
    const float* W_out  = (const float*)d_in[4];   // (512, D)
    const float* b_out  = (const float*)d_in[5];   // (D,)
    float* out = (float*)d_out;

    char* ws = (char*)d_ws;
    unsigned short* Vt   = (unsigned short*)ws;                                // 8.75 MB
    unsigned short* xbf  = (unsigned short*)(ws + (size_t)9  * 1024 * 1024);   // 8 MB (reused as attnOut)
    unsigned short* WvT  = (unsigned short*)(ws + (size_t)17 * 1024 * 1024);   // 512 KB
    unsigned short* WoT  = (unsigned short*)(ws + (size_t)17 * 1024 * 1024 + 524288);
    float*          l2r  = (float*)(ws + (size_t)18 * 1024 * 1024);            // 256 KB
    unsigned short* attnOut = xbf;   // xbf dead after GEMM1

    prep_fused<<<2240, 256, 0, stream>>>(x, W_sig, b_sig, W_v, W_out,
                                         xbf, l2r, WvT, WoT, Vt);

    // 1) Vt = (x @ W_v)^T, bf16, column-padded per batch
    {
        dim3 grid(128, 8);
        gemm_bf16<2><<<grid, 256, 0, stream>>>(WvT, xbf, nullptr, Vt, LDV);
    }
    // 2) banded MFMA attention (32x32, d-split) -> bf16 row-major O
    attn_mfma<<<1024, 256, 0, stream>>>(Vt, l2r, attnOut);
    // 3) out = attnOut @ W_out + b_out (f32), 1D grid 1024, XCD-swizzled
    gemm_bf16<0><<<1024, 256, 0, stream>>>(attnOut, WoT, b_out, out, D);
}